// Round 3
// baseline (2090.757 us; speedup 1.0000x reference)
//
#include <hip/hip_runtime.h>
#include <hip/hip_bf16.h>

#define KD 128

// ---------------- generic K=128 GEMM: C = act(A1[idx]@W1 (+A2[idx]@W2) (+bias)) (+Res[ridx]) ----
// 64 rows/block, NC cols, 256 threads, 4xCW per thread. K chunked at KB=32,
// reg-staged LDS double buffer (issue loads -> compute -> commit -> barrier).
template<int NC, bool HAS_A2, bool HAS_BIAS, bool DO_ELU, bool HAS_RES>
__global__ __launch_bounds__(256, 3) void gemm_k128(
    const float* __restrict__ A1, const float* __restrict__ W1,
    const float* __restrict__ A2, const float* __restrict__ W2,
    const float* __restrict__ bias, const float* __restrict__ Res,
    const int* __restrict__ aidx, const int* __restrict__ ridx,
    int M, float* __restrict__ C)
{
  constexpr int CW = NC / 16;           // cols per thread (8 for NC=128, 4 for NC=64)
  constexpr int KB = 32;                // K chunk
  constexpr int NWF4 = KB * NC / 4 / 256; // W float4s per thread per chunk (4 or 2)
  __shared__ float sA[2][64][KB + 4];   // row stride 36 floats (144B, 16B-aligned)
  __shared__ float sW[2][KB][NC];
  const int t  = threadIdx.x;
  const int ty = t >> 4, tx = t & 15;
  const int row0 = blockIdx.x * 64;

  float acc[4][CW];
  #pragma unroll
  for (int i = 0; i < 4; ++i)
    #pragma unroll
    for (int j = 0; j < CW; ++j) acc[i][j] = 0.f;

  const int npass = HAS_A2 ? 2 : 1;
  const int NCH = npass * 4;            // K=128 -> 4 chunks per pass

  float4 ra[2];
  float4 rw[NWF4];

  auto issue = [&](int cc) {
    const float* Am = (cc < 4) ? A1 : A2;
    const float* Wm = (cc < 4) ? W1 : W2;
    const int kc = cc & 3;
    #pragma unroll
    for (int q = 0; q < 2; ++q) {
      int p = t + 256 * q;              // 0..511
      int r = p >> 3, c4 = p & 7;       // 8 float4 per 32-float row slice
      ra[q] = make_float4(0.f, 0.f, 0.f, 0.f);
      int gr = row0 + r;
      if (gr < M) {
        long grow = aidx ? (long)aidx[gr] : (long)gr;
        ra[q] = reinterpret_cast<const float4*>(Am + grow * KD)[kc * 8 + c4];
      }
    }
    const float4* Wp = reinterpret_cast<const float4*>(Wm + (long)kc * KB * NC);
    #pragma unroll
    for (int q = 0; q < NWF4; ++q) rw[q] = Wp[t + 256 * q];
  };
  auto commit = [&](int cc) {
    const int b = cc & 1;
    #pragma unroll
    for (int q = 0; q < 2; ++q) {
      int p = t + 256 * q;
      int r = p >> 3, c4 = p & 7;
      *reinterpret_cast<float4*>(&sA[b][r][c4 * 4]) = ra[q];
    }
    #pragma unroll
    for (int q = 0; q < NWF4; ++q)
      reinterpret_cast<float4*>(&sW[b][0][0])[t + 256 * q] = rw[q];
  };

  issue(0);
  commit(0);
  __syncthreads();
  for (int cc = 0; cc < NCH; ++cc) {
    if (cc + 1 < NCH) issue(cc + 1);    // global loads overlap compute below
    const int b = cc & 1;
    #pragma unroll
    for (int k = 0; k < KB; ++k) {
      float a[4];
      float wv[CW];
      #pragma unroll
      for (int i = 0; i < 4; ++i) a[i] = sA[b][ty * 4 + i][k];
      #pragma unroll
      for (int h = 0; h < CW / 4; ++h) {
        float4 w4 = *reinterpret_cast<const float4*>(&sW[b][k][tx * 4 + 64 * h]);
        wv[h * 4 + 0] = w4.x; wv[h * 4 + 1] = w4.y; wv[h * 4 + 2] = w4.z; wv[h * 4 + 3] = w4.w;
      }
      #pragma unroll
      for (int i = 0; i < 4; ++i)
        #pragma unroll
        for (int j = 0; j < CW; ++j)
          acc[i][j] = fmaf(a[i], wv[j], acc[i][j]);
    }
    if (cc + 1 < NCH) {
      commit(cc + 1);
      __syncthreads();
    }
  }
  // epilogue: cols for thread = tx*4 + w + 64*h
  #pragma unroll
  for (int i = 0; i < 4; ++i) {
    int gr = row0 + ty * 4 + i;
    if (gr >= M) continue;
    long rrow = 0;
    if (HAS_RES) rrow = ridx ? (long)ridx[gr] : (long)gr;
    #pragma unroll
    for (int h = 0; h < CW / 4; ++h) {
      int c = tx * 4 + 64 * h;
      float4 v = make_float4(acc[i][h*4+0], acc[i][h*4+1], acc[i][h*4+2], acc[i][h*4+3]);
      if (HAS_BIAS) {
        float4 bv = *reinterpret_cast<const float4*>(bias + c);
        v.x += bv.x; v.y += bv.y; v.z += bv.z; v.w += bv.w;
      }
      if (DO_ELU) {
        v.x = (v.x > 0.f) ? v.x : (__expf(v.x) - 1.f);
        v.y = (v.y > 0.f) ? v.y : (__expf(v.y) - 1.f);
        v.z = (v.z > 0.f) ? v.z : (__expf(v.z) - 1.f);
        v.w = (v.w > 0.f) ? v.w : (__expf(v.w) - 1.f);
      }
      if (HAS_RES) {
        float4 rv = *reinterpret_cast<const float4*>(Res + rrow * NC + c);
        v.x += rv.x; v.y += rv.y; v.z += rv.z; v.w += rv.w;
      }
      *reinterpret_cast<float4*>(C + (long)gr * NC + c) = v;
    }
  }
}

// ---------------- per-node score projections: as = H1@a_s, an = H1@a_n -------------
__global__ __launch_bounds__(256) void proj_kernel(
    const float* __restrict__ H1, const float* __restrict__ a_s, const float* __restrict__ a_n,
    float* __restrict__ as_o, float* __restrict__ an_o, int M)
{
  int wid  = (int)((blockIdx.x * 256 + threadIdx.x) >> 6);
  int lane = threadIdx.x & 63;
  if (wid >= M) return;
  float2 h  = *reinterpret_cast<const float2*>(H1 + (long)wid * KD + lane * 2);
  float2 vs = *reinterpret_cast<const float2*>(a_s + lane * 2);
  float2 vn = *reinterpret_cast<const float2*>(a_n + lane * 2);
  float ps = h.x * vs.x + h.y * vs.y;
  float pn = h.x * vn.x + h.y * vn.y;
  #pragma unroll
  for (int o = 32; o > 0; o >>= 1) { ps += __shfl_xor(ps, o, 64); pn += __shfl_xor(pn, o, 64); }
  if (lane == 0) { as_o[wid] = ps; an_o[wid] = pn; }
}

// ---------------- needed-dst flags -------------
__global__ void flags_kernel(const int* __restrict__ ui, const int* __restrict__ ii, int B,
                             int* __restrict__ nfu, int* __restrict__ nfb)
{
  int i = blockIdx.x * blockDim.x + threadIdx.x;
  if (i < B) { nfu[ui[i]] = 1; nfb[ii[i]] = 1; }
}

// ---------------- omega edge weights -------------
__global__ void uw_kernel(const float* __restrict__ gc, const float* __restrict__ omega,
                          int E, float* __restrict__ uw)
{
  int e = blockIdx.x * blockDim.x + threadIdx.x;
  if (e < E) uw[e] = gc[(long)e*3+0]*omega[0] + gc[(long)e*3+1]*omega[1] + gc[(long)e*3+2]*omega[2];
}

// ---------------- grouping pass 1: per-dst degree (gated) -------------
__global__ __launch_bounds__(256) void count_kernel(
    const int* __restrict__ dst, const int* __restrict__ flag,
    int* __restrict__ deg, int E)
{
  int e = blockIdx.x * 256 + threadIdx.x;
  if (e >= E) return;
  int d = dst[e];
  if (flag[d]) atomicAdd(&deg[d], 1);
}

// ---------------- grouping pass 2: assign segment offsets + compact dst list ----
__global__ __launch_bounds__(256) void offset_kernel(
    const int* __restrict__ flag, const int* __restrict__ deg,
    int* __restrict__ offs, int* __restrict__ cur,
    int* __restrict__ dlist, int* __restrict__ cnt,
    float* __restrict__ Hout, int N)
{
  int i = blockIdx.x * 256 + threadIdx.x;
  if (i >= N || !flag[i]) return;
  int dg = deg[i];
  if (dg == 0) {
    // flagged node with no incoming edges: reference yields a zero row
    float4 z = make_float4(0.f, 0.f, 0.f, 0.f);
    float4* r = reinterpret_cast<float4*>(Hout + (long)i * KD);
    #pragma unroll
    for (int j = 0; j < KD / 4; ++j) r[j] = z;
    return;
  }
  int o = atomicAdd(&cnt[0], dg);
  int l = atomicAdd(&cnt[1], 1);
  offs[i] = o;
  cur[i]  = o;
  dlist[l] = i;
}

// ---------------- grouping pass 3: scatter (src, leaky score) into groups ----
__global__ __launch_bounds__(256) void scatter_kernel(
    const int* __restrict__ src, const int* __restrict__ dst,
    const int* __restrict__ flag,
    const float* __restrict__ as_, const float* __restrict__ an_,
    const float* __restrict__ uw, int* __restrict__ cur,
    int* __restrict__ esrc, float* __restrict__ esc, int E)
{
  int e = blockIdx.x * 256 + threadIdx.x;
  if (e >= E) return;
  int d = dst[e];
  if (!flag[d]) return;
  int s = src[e];
  float sc = as_[d] + an_[s];
  if (uw) sc *= uw[e];
  sc = (sc >= 0.f) ? sc : 0.2f * sc;   // leaky_relu 0.2
  int pos = atomicAdd(&cur[d], 1);
  esrc[pos] = s;
  esc[pos]  = sc;
}

// ---------------- wave-per-dst softmax + aggregation (no feature atomics) ----
__global__ __launch_bounds__(256) void aggr_kernel(
    const int* __restrict__ dlist, const int* __restrict__ cnt,
    const int* __restrict__ offs, const int* __restrict__ deg,
    const int* __restrict__ esrc, const float* __restrict__ esc,
    const float* __restrict__ H1, float* __restrict__ Hout)
{
  int wid  = (int)((blockIdx.x * 256 + threadIdx.x) >> 6);
  int lane = threadIdx.x & 63;
  if (wid >= cnt[1]) return;
  int d  = dlist[wid];
  int st = offs[d];
  int n  = deg[d];
  // segment max
  float m = -3.4e38f;
  for (int i = lane; i < n; i += 64) m = fmaxf(m, esc[st + i]);
  #pragma unroll
  for (int o = 32; o; o >>= 1) m = fmaxf(m, __shfl_xor(m, o, 64));
  // segment sum of exp
  float s = 0.f;
  for (int i = lane; i < n; i += 64) s += __expf(esc[st + i] - m);
  #pragma unroll
  for (int o = 32; o; o >>= 1) s += __shfl_xor(s, o, 64);
  float inv = 1.f / s;
  // weighted aggregation: each lane owns 2 columns; rows read coalesced
  float ax = 0.f, ay = 0.f;
  int i = 0;
  for (; i + 2 <= n; i += 2) {
    float a0 = __expf(esc[st + i]     - m);
    float a1 = __expf(esc[st + i + 1] - m);
    const float2 h0 = *reinterpret_cast<const float2*>(H1 + (long)esrc[st + i]     * KD + lane * 2);
    const float2 h1 = *reinterpret_cast<const float2*>(H1 + (long)esrc[st + i + 1] * KD + lane * 2);
    ax = fmaf(h0.x, a0, ax); ay = fmaf(h0.y, a0, ay);
    ax = fmaf(h1.x, a1, ax); ay = fmaf(h1.y, a1, ay);
  }
  if (i < n) {
    float a0 = __expf(esc[st + i] - m);
    const float2 h0 = *reinterpret_cast<const float2*>(H1 + (long)esrc[st + i] * KD + lane * 2);
    ax = fmaf(h0.x, a0, ax); ay = fmaf(h0.y, a0, ay);
  }
  *reinterpret_cast<float2*>(Hout + (long)d * KD + lane * 2) = make_float2(ax * inv, ay * inv);
}

// ---------------- final: dot + biases + sigmoid -------------
__global__ __launch_bounds__(256) void final_kernel(
    const float* __restrict__ Ug, const float* __restrict__ Bg,
    const int* __restrict__ ui, const int* __restrict__ ii,
    const float* __restrict__ bias_u, const float* __restrict__ bias_b,
    const float* __restrict__ bx, float* __restrict__ out, int B)
{
  int wid  = (int)((blockIdx.x * 256 + threadIdx.x) >> 6);
  int lane = threadIdx.x & 63;
  if (wid >= B) return;
  float v = Ug[(long)wid * 64 + lane] * Bg[(long)wid * 64 + lane];
  #pragma unroll
  for (int o = 32; o > 0; o >>= 1) v += __shfl_xor(v, o, 64);
  if (lane == 0) {
    float raw = v + bias_u[ui[wid]] + bias_b[ii[wid]] + bx[0];
    out[wid] = 4.f / (1.f + __expf(-raw)) + 1.f;
  }
}

extern "C" void kernel_launch(void* const* d_in, const int* in_sizes, int n_in,
                              void* d_out, int out_size, void* d_ws, size_t ws_size,
                              hipStream_t stream)
{
  const int*   ui    = (const int*)  d_in[0];
  const int*   ii    = (const int*)  d_in[1];
  const float* S_u   = (const float*)d_in[2];
  const float* S_b   = (const float*)d_in[3];
  const int*   eu    = (const int*)  d_in[4];
  const int*   eb    = (const int*)  d_in[5];
  const float* gc    = (const float*)d_in[6];
  const float* W1_u  = (const float*)d_in[7];
  const float* a_s_u = (const float*)d_in[8];
  const float* a_n_u = (const float*)d_in[9];
  const float* W1_b  = (const float*)d_in[10];
  const float* a_s_b = (const float*)d_in[11];
  const float* a_n_b = (const float*)d_in[12];
  const float* omega = (const float*)d_in[13];
  const float* W_u2  = (const float*)d_in[14];
  const float* W_us2w= (const float*)d_in[15];
  const float* W_us2b= (const float*)d_in[16];
  const float* W_b2  = (const float*)d_in[17];
  const float* W_bs2w= (const float*)d_in[18];
  const float* W_bs2b= (const float*)d_in[19];
  const float* W_u3  = (const float*)d_in[20];
  const float* W_b3  = (const float*)d_in[21];
  const float* H_u4  = (const float*)d_in[22];
  const float* H_b4  = (const float*)d_in[23];
  const float* bias_u= (const float*)d_in[24];
  const float* bias_b= (const float*)d_in[25];
  const float* b_x   = (const float*)d_in[26];
  float* out = (float*)d_out;

  const int B  = in_sizes[0];
  const int NU = in_sizes[2] / KD;
  const int NI = in_sizes[3] / KD;
  const int EU = in_sizes[4] / 2;
  const int EB = in_sizes[5] / 2;

  char* w = (char*)d_ws;
  auto alloc = [&](size_t bytes) -> void* {
    void* r = (void*)w;
    w += (bytes + 255) & ~(size_t)255;
    return r;
  };
  // ---- zero-initialized region (one small memset per call) ----
  int* deg_u = (int*)alloc((size_t)NU * 4);
  int* deg_b = (int*)alloc((size_t)NI * 4);
  int* nfu   = (int*)alloc((size_t)NU * 4);
  int* nfb   = (int*)alloc((size_t)NI * 4);
  int* cnt   = (int*)alloc(16 * 4);          // [0,1]=user {edges,dsts}, [2,3]=item
  size_t zbytes = (size_t)(w - (char*)d_ws);
  // ---- scratch (fully written before read each call) ----
  int*   offs_u = (int*)  alloc((size_t)NU * 4);
  int*   cur_u  = (int*)  alloc((size_t)NU * 4);
  int*   offs_b = (int*)  alloc((size_t)NI * 4);
  int*   cur_b  = (int*)  alloc((size_t)NI * 4);
  int*   dl_u   = (int*)  alloc((size_t)B * 4);
  int*   dl_b   = (int*)  alloc((size_t)B * 4);
  int*   esrc_u = (int*)  alloc((size_t)EU * 4);
  float* esc_u  = (float*)alloc((size_t)EU * 4);
  int*   esrc_b = (int*)  alloc((size_t)EB * 4);
  float* esc_b  = (float*)alloc((size_t)EB * 4);
  float* H1u  = (float*)alloc((size_t)NU * KD * 4);
  float* H1b  = (float*)alloc((size_t)NI * KD * 4);
  float* Hu2  = (float*)alloc((size_t)NU * KD * 4);
  float* Hb2  = (float*)alloc((size_t)NI * KD * 4);
  float* asu  = (float*)alloc((size_t)NU * 4);
  float* anu  = (float*)alloc((size_t)NU * 4);
  float* asb  = (float*)alloc((size_t)NI * 4);
  float* anb  = (float*)alloc((size_t)NI * 4);
  float* uwv  = (float*)alloc((size_t)EB * 4);
  float* Hu3g = (float*)alloc((size_t)B * KD * 4);
  float* Hb3g = (float*)alloc((size_t)B * KD * 4);
  float* Ug   = (float*)alloc((size_t)B * 64 * 4);
  float* Bg   = (float*)alloc((size_t)B * 64 * 4);
  (void)ws_size; (void)n_in; (void)out_size;

  hipMemsetAsync(d_ws, 0, zbytes, stream);

  flags_kernel<<<(B + 255) / 256, 256, 0, stream>>>(ui, ii, B, nfu, nfb);
  uw_kernel<<<(EB + 255) / 256, 256, 0, stream>>>(gc, omega, EB, uwv);

  gemm_k128<128,false,false,false,false><<<(NU + 63) / 64, 256, 0, stream>>>(
      S_u, W1_u, nullptr, nullptr, nullptr, nullptr, nullptr, nullptr, NU, H1u);
  gemm_k128<128,false,false,false,false><<<(NI + 63) / 64, 256, 0, stream>>>(
      S_b, W1_b, nullptr, nullptr, nullptr, nullptr, nullptr, nullptr, NI, H1b);

  proj_kernel<<<(NU + 3) / 4, 256, 0, stream>>>(H1u, a_s_u, a_n_u, asu, anu, NU);
  proj_kernel<<<(NI + 3) / 4, 256, 0, stream>>>(H1b, a_s_b, a_n_b, asb, anb, NI);

  count_kernel<<<(EU + 255) / 256, 256, 0, stream>>>(eu + EU, nfu, deg_u, EU);
  count_kernel<<<(EB + 255) / 256, 256, 0, stream>>>(eb + EB, nfb, deg_b, EB);

  offset_kernel<<<(NU + 255) / 256, 256, 0, stream>>>(nfu, deg_u, offs_u, cur_u, dl_u, cnt + 0, Hu2, NU);
  offset_kernel<<<(NI + 255) / 256, 256, 0, stream>>>(nfb, deg_b, offs_b, cur_b, dl_b, cnt + 2, Hb2, NI);

  scatter_kernel<<<(EU + 255) / 256, 256, 0, stream>>>(eu, eu + EU, nfu, asu, anu, nullptr, cur_u, esrc_u, esc_u, EU);
  scatter_kernel<<<(EB + 255) / 256, 256, 0, stream>>>(eb, eb + EB, nfb, asb, anb, uwv, cur_b, esrc_b, esc_b, EB);

  aggr_kernel<<<(B * 64 + 255) / 256, 256, 0, stream>>>(dl_u, cnt + 0, offs_u, deg_u, esrc_u, esc_u, H1u, Hu2);
  aggr_kernel<<<(B * 64 + 255) / 256, 256, 0, stream>>>(dl_b, cnt + 2, offs_b, deg_b, esrc_b, esc_b, H1b, Hb2);

  gemm_k128<128,true,true,true,false><<<(B + 63) / 64, 256, 0, stream>>>(
      Hu2, W_u2, S_u, W_us2w, W_us2b, nullptr, ui, nullptr, B, Hu3g);
  gemm_k128<128,true,true,true,false><<<(B + 63) / 64, 256, 0, stream>>>(
      Hb2, W_b2, S_b, W_bs2w, W_bs2b, nullptr, ii, nullptr, B, Hb3g);

  gemm_k128<64,false,false,true,true><<<(B + 63) / 64, 256, 0, stream>>>(
      Hu3g, W_u3, nullptr, nullptr, nullptr, H_u4, nullptr, ui, B, Ug);
  gemm_k128<64,false,false,true,true><<<(B + 63) / 64, 256, 0, stream>>>(
      Hb3g, W_b3, nullptr, nullptr, nullptr, H_b4, nullptr, ii, B, Bg);

  final_kernel<<<(B + 3) / 4, 256, 0, stream>>>(Ug, Bg, ui, ii, bias_u, bias_b, b_x, out, B);
}

// Round 4
// 527.988 us; speedup vs baseline: 3.9599x; 3.9599x over previous
//
#include <hip/hip_runtime.h>
#include <hip/hip_bf16.h>

#define KD 128

// ---------------- generic K=128 GEMM: C = act(A1[idx]@W1 (+A2[idx]@W2) (+bias)) (+Res[ridx]) ----
// 64 rows/block, NC cols, 256 threads, thread tile 4x(NC/16). K chunked at KB=64,
// single-buffered LDS (stage -> barrier -> compute -> barrier). ~49KB LDS -> 3 blocks/CU.
template<int NC, bool HAS_A2, bool HAS_BIAS, bool DO_ELU, bool HAS_RES>
__global__ __launch_bounds__(256, 3) void gemm_k128(
    const float* __restrict__ A1, const float* __restrict__ W1,
    const float* __restrict__ A2, const float* __restrict__ W2,
    const float* __restrict__ bias, const float* __restrict__ Res,
    const int* __restrict__ aidx, const int* __restrict__ ridx,
    int M, float* __restrict__ C)
{
  constexpr int CW = NC / 16;            // cols per thread (8 for NC=128, 4 for NC=64)
  constexpr int KB = 64;                 // K chunk
  constexpr int NAF4 = 64 * KB / 4 / 256;   // A float4s per thread per chunk (4)
  constexpr int NWF4 = KB * NC / 4 / 256;   // W float4s per thread per chunk (8 or 4)
  __shared__ float sA[64][KB + 4];       // row stride 68 floats; +4 keeps 16B align & bank spread
  __shared__ float sW[KB][NC];
  const int t  = threadIdx.x;
  const int ty = t >> 4, tx = t & 15;
  const int row0 = blockIdx.x * 64;

  float acc[4][CW];
  #pragma unroll
  for (int i = 0; i < 4; ++i)
    #pragma unroll
    for (int j = 0; j < CW; ++j) acc[i][j] = 0.f;

  const int npass = HAS_A2 ? 2 : 1;
  const int NCH = npass * (KD / KB);     // 2 chunks per pass

  for (int cc = 0; cc < NCH; ++cc) {
    const float* Am = (cc < 2) ? A1 : A2;
    const float* Wm = (cc < 2) ? W1 : W2;
    const int kc = cc & 1;               // K chunk index within pass
    if (cc) __syncthreads();             // previous compute done before overwrite
    // stage W chunk: rows [kc*KB, kc*KB+KB) x NC, linear float4, coalesced
    {
      const float4* Wp = reinterpret_cast<const float4*>(Wm) + (long)kc * (KB * NC / 4);
      #pragma unroll
      for (int q = 0; q < NWF4; ++q)
        reinterpret_cast<float4*>(&sW[0][0])[t + 256 * q] = Wp[t + 256 * q];
    }
    // stage A chunk: 64 rows x KB cols, row-major, coalesced 16 lanes/row
    #pragma unroll
    for (int q = 0; q < NAF4; ++q) {
      int p  = t + 256 * q;
      int r  = p >> 4, c4 = p & 15;
      float4 v = make_float4(0.f, 0.f, 0.f, 0.f);
      int gr = row0 + r;
      if (gr < M) {
        long grow = aidx ? (long)aidx[gr] : (long)gr;
        v = reinterpret_cast<const float4*>(Am + grow * KD)[kc * (KB / 4) + c4];
      }
      *reinterpret_cast<float4*>(&sA[r][c4 * 4]) = v;
    }
    __syncthreads();
    #pragma unroll 4
    for (int k = 0; k < KB; ++k) {
      float a[4];
      float wv[CW];
      #pragma unroll
      for (int i = 0; i < 4; ++i) a[i] = sA[ty * 4 + i][k];   // 4 addrs/wave, broadcast
      #pragma unroll
      for (int h = 0; h < CW / 4; ++h) {
        float4 w4 = *reinterpret_cast<const float4*>(&sW[k][tx * 4 + 64 * h]);
        wv[h * 4 + 0] = w4.x; wv[h * 4 + 1] = w4.y; wv[h * 4 + 2] = w4.z; wv[h * 4 + 3] = w4.w;
      }
      #pragma unroll
      for (int i = 0; i < 4; ++i)
        #pragma unroll
        for (int j = 0; j < CW; ++j)
          acc[i][j] = fmaf(a[i], wv[j], acc[i][j]);
    }
  }
  // epilogue: cols for thread = tx*4 + 64*h, float4 stores
  #pragma unroll
  for (int i = 0; i < 4; ++i) {
    int gr = row0 + ty * 4 + i;
    if (gr >= M) continue;
    long rrow = 0;
    if (HAS_RES) rrow = ridx ? (long)ridx[gr] : (long)gr;
    #pragma unroll
    for (int h = 0; h < CW / 4; ++h) {
      int c = tx * 4 + 64 * h;
      float4 v = make_float4(acc[i][h*4+0], acc[i][h*4+1], acc[i][h*4+2], acc[i][h*4+3]);
      if (HAS_BIAS) {
        float4 bv = *reinterpret_cast<const float4*>(bias + c);
        v.x += bv.x; v.y += bv.y; v.z += bv.z; v.w += bv.w;
      }
      if (DO_ELU) {
        v.x = (v.x > 0.f) ? v.x : (__expf(v.x) - 1.f);
        v.y = (v.y > 0.f) ? v.y : (__expf(v.y) - 1.f);
        v.z = (v.z > 0.f) ? v.z : (__expf(v.z) - 1.f);
        v.w = (v.w > 0.f) ? v.w : (__expf(v.w) - 1.f);
      }
      if (HAS_RES) {
        float4 rv = *reinterpret_cast<const float4*>(Res + rrow * NC + c);
        v.x += rv.x; v.y += rv.y; v.z += rv.z; v.w += rv.w;
      }
      *reinterpret_cast<float4*>(C + (long)gr * NC + c) = v;
    }
  }
}

// ---------------- per-node score projections: as = H1@a_s, an = H1@a_n -------------
__global__ __launch_bounds__(256) void proj_kernel(
    const float* __restrict__ H1, const float* __restrict__ a_s, const float* __restrict__ a_n,
    float* __restrict__ as_o, float* __restrict__ an_o, int M)
{
  int wid  = (int)((blockIdx.x * 256 + threadIdx.x) >> 6);
  int lane = threadIdx.x & 63;
  if (wid >= M) return;
  float2 h  = *reinterpret_cast<const float2*>(H1 + (long)wid * KD + lane * 2);
  float2 vs = *reinterpret_cast<const float2*>(a_s + lane * 2);
  float2 vn = *reinterpret_cast<const float2*>(a_n + lane * 2);
  float ps = h.x * vs.x + h.y * vs.y;
  float pn = h.x * vn.x + h.y * vn.y;
  #pragma unroll
  for (int o = 32; o > 0; o >>= 1) { ps += __shfl_xor(ps, o, 64); pn += __shfl_xor(pn, o, 64); }
  if (lane == 0) { as_o[wid] = ps; an_o[wid] = pn; }
}

// ---------------- needed-dst flags -------------
__global__ void flags_kernel(const int* __restrict__ ui, const int* __restrict__ ii, int B,
                             int* __restrict__ nfu, int* __restrict__ nfb)
{
  int i = blockIdx.x * blockDim.x + threadIdx.x;
  if (i < B) { nfu[ui[i]] = 1; nfb[ii[i]] = 1; }
}

// ---------------- omega edge weights -------------
__global__ void uw_kernel(const float* __restrict__ gc, const float* __restrict__ omega,
                          int E, float* __restrict__ uw)
{
  int e = blockIdx.x * blockDim.x + threadIdx.x;
  if (e < E) uw[e] = gc[(long)e*3+0]*omega[0] + gc[(long)e*3+1]*omega[1] + gc[(long)e*3+2]*omega[2];
}

// ---------------- grouping pass 1: per-dst degree (gated) -------------
__global__ __launch_bounds__(256) void count_kernel(
    const int* __restrict__ dst, const int* __restrict__ flag,
    int* __restrict__ deg, int E)
{
  int e = blockIdx.x * 256 + threadIdx.x;
  if (e >= E) return;
  int d = dst[e];
  if (flag[d]) atomicAdd(&deg[d], 1);
}

// ---------------- grouping pass 2: assign segment offsets + compact dst list ----
__global__ __launch_bounds__(256) void offset_kernel(
    const int* __restrict__ flag, const int* __restrict__ deg,
    int* __restrict__ offs, int* __restrict__ cur,
    int* __restrict__ dlist, int* __restrict__ cnt,
    float* __restrict__ Hout, int N)
{
  int i = blockIdx.x * 256 + threadIdx.x;
  if (i >= N || !flag[i]) return;
  int dg = deg[i];
  if (dg == 0) {
    // flagged node with no incoming edges: reference yields a zero row
    float4 z = make_float4(0.f, 0.f, 0.f, 0.f);
    float4* r = reinterpret_cast<float4*>(Hout + (long)i * KD);
    #pragma unroll
    for (int j = 0; j < KD / 4; ++j) r[j] = z;
    return;
  }
  int o = atomicAdd(&cnt[0], dg);
  int l = atomicAdd(&cnt[1], 1);
  offs[i] = o;
  cur[i]  = o;
  dlist[l] = i;
}

// ---------------- grouping pass 3: scatter (src, leaky score) into groups ----
__global__ __launch_bounds__(256) void scatter_kernel(
    const int* __restrict__ src, const int* __restrict__ dst,
    const int* __restrict__ flag,
    const float* __restrict__ as_, const float* __restrict__ an_,
    const float* __restrict__ uw, int* __restrict__ cur,
    int* __restrict__ esrc, float* __restrict__ esc, int E)
{
  int e = blockIdx.x * 256 + threadIdx.x;
  if (e >= E) return;
  int d = dst[e];
  if (!flag[d]) return;
  int s = src[e];
  float sc = as_[d] + an_[s];
  if (uw) sc *= uw[e];
  sc = (sc >= 0.f) ? sc : 0.2f * sc;   // leaky_relu 0.2
  int pos = atomicAdd(&cur[d], 1);
  esrc[pos] = s;
  esc[pos]  = sc;
}

// ---------------- wave-per-dst softmax + aggregation (no feature atomics) ----
__global__ __launch_bounds__(256) void aggr_kernel(
    const int* __restrict__ dlist, const int* __restrict__ cnt,
    const int* __restrict__ offs, const int* __restrict__ deg,
    const int* __restrict__ esrc, const float* __restrict__ esc,
    const float* __restrict__ H1, float* __restrict__ Hout)
{
  int wid  = (int)((blockIdx.x * 256 + threadIdx.x) >> 6);
  int lane = threadIdx.x & 63;
  if (wid >= cnt[1]) return;
  int d  = dlist[wid];
  int st = offs[d];
  int n  = deg[d];
  // segment max
  float m = -3.4e38f;
  for (int i = lane; i < n; i += 64) m = fmaxf(m, esc[st + i]);
  #pragma unroll
  for (int o = 32; o; o >>= 1) m = fmaxf(m, __shfl_xor(m, o, 64));
  // segment sum of exp
  float s = 0.f;
  for (int i = lane; i < n; i += 64) s += __expf(esc[st + i] - m);
  #pragma unroll
  for (int o = 32; o; o >>= 1) s += __shfl_xor(s, o, 64);
  float inv = 1.f / s;
  // weighted aggregation: each lane owns 2 columns; rows read coalesced
  float ax = 0.f, ay = 0.f;
  int i = 0;
  for (; i + 2 <= n; i += 2) {
    float a0 = __expf(esc[st + i]     - m);
    float a1 = __expf(esc[st + i + 1] - m);
    const float2 h0 = *reinterpret_cast<const float2*>(H1 + (long)esrc[st + i]     * KD + lane * 2);
    const float2 h1 = *reinterpret_cast<const float2*>(H1 + (long)esrc[st + i + 1] * KD + lane * 2);
    ax = fmaf(h0.x, a0, ax); ay = fmaf(h0.y, a0, ay);
    ax = fmaf(h1.x, a1, ax); ay = fmaf(h1.y, a1, ay);
  }
  if (i < n) {
    float a0 = __expf(esc[st + i] - m);
    const float2 h0 = *reinterpret_cast<const float2*>(H1 + (long)esrc[st + i] * KD + lane * 2);
    ax = fmaf(h0.x, a0, ax); ay = fmaf(h0.y, a0, ay);
  }
  *reinterpret_cast<float2*>(Hout + (long)d * KD + lane * 2) = make_float2(ax * inv, ay * inv);
}

// ---------------- final: dot + biases + sigmoid -------------
__global__ __launch_bounds__(256) void final_kernel(
    const float* __restrict__ Ug, const float* __restrict__ Bg,
    const int* __restrict__ ui, const int* __restrict__ ii,
    const float* __restrict__ bias_u, const float* __restrict__ bias_b,
    const float* __restrict__ bx, float* __restrict__ out, int B)
{
  int wid  = (int)((blockIdx.x * 256 + threadIdx.x) >> 6);
  int lane = threadIdx.x & 63;
  if (wid >= B) return;
  float v = Ug[(long)wid * 64 + lane] * Bg[(long)wid * 64 + lane];
  #pragma unroll
  for (int o = 32; o > 0; o >>= 1) v += __shfl_xor(v, o, 64);
  if (lane == 0) {
    float raw = v + bias_u[ui[wid]] + bias_b[ii[wid]] + bx[0];
    out[wid] = 4.f / (1.f + __expf(-raw)) + 1.f;
  }
}

extern "C" void kernel_launch(void* const* d_in, const int* in_sizes, int n_in,
                              void* d_out, int out_size, void* d_ws, size_t ws_size,
                              hipStream_t stream)
{
  const int*   ui    = (const int*)  d_in[0];
  const int*   ii    = (const int*)  d_in[1];
  const float* S_u   = (const float*)d_in[2];
  const float* S_b   = (const float*)d_in[3];
  const int*   eu    = (const int*)  d_in[4];
  const int*   eb    = (const int*)  d_in[5];
  const float* gc    = (const float*)d_in[6];
  const float* W1_u  = (const float*)d_in[7];
  const float* a_s_u = (const float*)d_in[8];
  const float* a_n_u = (const float*)d_in[9];
  const float* W1_b  = (const float*)d_in[10];
  const float* a_s_b = (const float*)d_in[11];
  const float* a_n_b = (const float*)d_in[12];
  const float* omega = (const float*)d_in[13];
  const float* W_u2  = (const float*)d_in[14];
  const float* W_us2w= (const float*)d_in[15];
  const float* W_us2b= (const float*)d_in[16];
  const float* W_b2  = (const float*)d_in[17];
  const float* W_bs2w= (const float*)d_in[18];
  const float* W_bs2b= (const float*)d_in[19];
  const float* W_u3  = (const float*)d_in[20];
  const float* W_b3  = (const float*)d_in[21];
  const float* H_u4  = (const float*)d_in[22];
  const float* H_b4  = (const float*)d_in[23];
  const float* bias_u= (const float*)d_in[24];
  const float* bias_b= (const float*)d_in[25];
  const float* b_x   = (const float*)d_in[26];
  float* out = (float*)d_out;

  const int B  = in_sizes[0];
  const int NU = in_sizes[2] / KD;
  const int NI = in_sizes[3] / KD;
  const int EU = in_sizes[4] / 2;
  const int EB = in_sizes[5] / 2;

  char* w = (char*)d_ws;
  auto alloc = [&](size_t bytes) -> void* {
    void* r = (void*)w;
    w += (bytes + 255) & ~(size_t)255;
    return r;
  };
  // ---- zero-initialized region (one small memset per call) ----
  int* deg_u = (int*)alloc((size_t)NU * 4);
  int* deg_b = (int*)alloc((size_t)NI * 4);
  int* nfu   = (int*)alloc((size_t)NU * 4);
  int* nfb   = (int*)alloc((size_t)NI * 4);
  int* cnt   = (int*)alloc(16 * 4);          // [0,1]=user {edges,dsts}, [2,3]=item
  size_t zbytes = (size_t)(w - (char*)d_ws);
  // ---- scratch (fully written before read each call) ----
  int*   offs_u = (int*)  alloc((size_t)NU * 4);
  int*   cur_u  = (int*)  alloc((size_t)NU * 4);
  int*   offs_b = (int*)  alloc((size_t)NI * 4);
  int*   cur_b  = (int*)  alloc((size_t)NI * 4);
  int*   dl_u   = (int*)  alloc((size_t)B * 4);
  int*   dl_b   = (int*)  alloc((size_t)B * 4);
  int*   esrc_u = (int*)  alloc((size_t)EU * 4);
  float* esc_u  = (float*)alloc((size_t)EU * 4);
  int*   esrc_b = (int*)  alloc((size_t)EB * 4);
  float* esc_b  = (float*)alloc((size_t)EB * 4);
  float* H1u  = (float*)alloc((size_t)NU * KD * 4);
  float* H1b  = (float*)alloc((size_t)NI * KD * 4);
  float* Hu2  = (float*)alloc((size_t)NU * KD * 4);
  float* Hb2  = (float*)alloc((size_t)NI * KD * 4);
  float* asu  = (float*)alloc((size_t)NU * 4);
  float* anu  = (float*)alloc((size_t)NU * 4);
  float* asb  = (float*)alloc((size_t)NI * 4);
  float* anb  = (float*)alloc((size_t)NI * 4);
  float* uwv  = (float*)alloc((size_t)EB * 4);
  float* Hu3g = (float*)alloc((size_t)B * KD * 4);
  float* Hb3g = (float*)alloc((size_t)B * KD * 4);
  float* Ug   = (float*)alloc((size_t)B * 64 * 4);
  float* Bg   = (float*)alloc((size_t)B * 64 * 4);
  (void)ws_size; (void)n_in; (void)out_size;

  hipMemsetAsync(d_ws, 0, zbytes, stream);

  flags_kernel<<<(B + 255) / 256, 256, 0, stream>>>(ui, ii, B, nfu, nfb);
  uw_kernel<<<(EB + 255) / 256, 256, 0, stream>>>(gc, omega, EB, uwv);

  gemm_k128<128,false,false,false,false><<<(NU + 63) / 64, 256, 0, stream>>>(
      S_u, W1_u, nullptr, nullptr, nullptr, nullptr, nullptr, nullptr, NU, H1u);
  gemm_k128<128,false,false,false,false><<<(NI + 63) / 64, 256, 0, stream>>>(
      S_b, W1_b, nullptr, nullptr, nullptr, nullptr, nullptr, nullptr, NI, H1b);

  proj_kernel<<<(NU + 3) / 4, 256, 0, stream>>>(H1u, a_s_u, a_n_u, asu, anu, NU);
  proj_kernel<<<(NI + 3) / 4, 256, 0, stream>>>(H1b, a_s_b, a_n_b, asb, anb, NI);

  count_kernel<<<(EU + 255) / 256, 256, 0, stream>>>(eu + EU, nfu, deg_u, EU);
  count_kernel<<<(EB + 255) / 256, 256, 0, stream>>>(eb + EB, nfb, deg_b, EB);

  offset_kernel<<<(NU + 255) / 256, 256, 0, stream>>>(nfu, deg_u, offs_u, cur_u, dl_u, cnt + 0, Hu2, NU);
  offset_kernel<<<(NI + 255) / 256, 256, 0, stream>>>(nfb, deg_b, offs_b, cur_b, dl_b, cnt + 2, Hb2, NI);

  scatter_kernel<<<(EU + 255) / 256, 256, 0, stream>>>(eu, eu + EU, nfu, asu, anu, nullptr, cur_u, esrc_u, esc_u, EU);
  scatter_kernel<<<(EB + 255) / 256, 256, 0, stream>>>(eb, eb + EB, nfb, asb, anb, uwv, cur_b, esrc_b, esc_b, EB);

  aggr_kernel<<<(B * 64 + 255) / 256, 256, 0, stream>>>(dl_u, cnt + 0, offs_u, deg_u, esrc_u, esc_u, H1u, Hu2);
  aggr_kernel<<<(B * 64 + 255) / 256, 256, 0, stream>>>(dl_b, cnt + 2, offs_b, deg_b, esrc_b, esc_b, H1b, Hb2);

  gemm_k128<128,true,true,true,false><<<(B + 63) / 64, 256, 0, stream>>>(
      Hu2, W_u2, S_u, W_us2w, W_us2b, nullptr, ui, nullptr, B, Hu3g);
  gemm_k128<128,true,true,true,false><<<(B + 63) / 64, 256, 0, stream>>>(
      Hb2, W_b2, S_b, W_bs2w, W_bs2b, nullptr, ii, nullptr, B, Hb3g);

  gemm_k128<64,false,false,true,true><<<(B + 63) / 64, 256, 0, stream>>>(
      Hu3g, W_u3, nullptr, nullptr, nullptr, H_u4, nullptr, ui, B, Ug);
  gemm_k128<64,false,false,true,true><<<(B + 63) / 64, 256, 0, stream>>>(
      Hb3g, W_b3, nullptr, nullptr, nullptr, H_b4, nullptr, ii, B, Bg);

  final_kernel<<<(B + 3) / 4, 256, 0, stream>>>(Ug, Bg, ui, ii, bias_u, bias_b, b_x, out, B);
}

// Round 5
// 452.209 us; speedup vs baseline: 4.6234x; 1.1676x over previous
//
#include <hip/hip_runtime.h>
#include <hip/hip_bf16.h>

#define KD 128

// ---------------- generic K=128 GEMM: C = act(A1[map1[idx]]@W1 (+A2[idx]@W2) (+bias)) (+Res[ridx])
// Optional fused projections: as_o = row@a_s, an_o = row@a_n (for the H1 GAT gemm).
// 64 rows/block, NC cols, 256 threads, thread tile 4x(NC/16). K chunked at KB=64,
// single-buffered LDS (stage -> barrier -> compute -> barrier). ~49KB LDS -> 3 blocks/CU.
template<int NC, bool HAS_A2, bool HAS_BIAS, bool DO_ELU, bool HAS_RES, bool DO_PROJ>
__global__ __launch_bounds__(256, 3) void gemm_k128(
    const float* __restrict__ A1, const float* __restrict__ W1,
    const float* __restrict__ A2, const float* __restrict__ W2,
    const float* __restrict__ bias, const float* __restrict__ Res,
    const int* __restrict__ aidx, const int* __restrict__ map1,
    const int* __restrict__ ridx,
    int M, float* __restrict__ C,
    const float* __restrict__ a_s, const float* __restrict__ a_n,
    float* __restrict__ as_o, float* __restrict__ an_o)
{
  constexpr int CW = NC / 16;            // cols per thread (8 for NC=128, 4 for NC=64)
  constexpr int KB = 64;                 // K chunk
  constexpr int NAF4 = 64 * KB / 4 / 256;   // A float4s per thread per chunk (4)
  constexpr int NWF4 = KB * NC / 4 / 256;   // W float4s per thread per chunk (8 or 4)
  __shared__ float sA[64][KB + 4];       // row stride 68 floats
  __shared__ float sW[KB][NC];
  const int t  = threadIdx.x;
  const int ty = t >> 4, tx = t & 15;
  const int row0 = blockIdx.x * 64;

  float acc[4][CW];
  #pragma unroll
  for (int i = 0; i < 4; ++i)
    #pragma unroll
    for (int j = 0; j < CW; ++j) acc[i][j] = 0.f;

  const int npass = HAS_A2 ? 2 : 1;
  const int NCH = npass * (KD / KB);     // 2 chunks per pass

  for (int cc = 0; cc < NCH; ++cc) {
    const float* Am = (cc < 2) ? A1 : A2;
    const float* Wm = (cc < 2) ? W1 : W2;
    const int* mp   = (cc < 2) ? map1 : nullptr;
    const int kc = cc & 1;               // K chunk index within pass
    if (cc) __syncthreads();             // previous compute done before overwrite
    // stage W chunk: rows [kc*KB, kc*KB+KB) x NC, linear float4, coalesced
    {
      const float4* Wp = reinterpret_cast<const float4*>(Wm) + (long)kc * (KB * NC / 4);
      #pragma unroll
      for (int q = 0; q < NWF4; ++q)
        reinterpret_cast<float4*>(&sW[0][0])[t + 256 * q] = Wp[t + 256 * q];
    }
    // stage A chunk: 64 rows x KB cols, row-major, coalesced 16 lanes/row
    #pragma unroll
    for (int q = 0; q < NAF4; ++q) {
      int p  = t + 256 * q;
      int r  = p >> 4, c4 = p & 15;
      float4 v = make_float4(0.f, 0.f, 0.f, 0.f);
      int gr = row0 + r;
      if (gr < M) {
        long grow = aidx ? (long)aidx[gr] : (long)gr;
        if (mp) grow = mp[grow];
        v = reinterpret_cast<const float4*>(Am + grow * KD)[kc * (KB / 4) + c4];
      }
      *reinterpret_cast<float4*>(&sA[r][c4 * 4]) = v;
    }
    __syncthreads();
    #pragma unroll 4
    for (int k = 0; k < KB; ++k) {
      float a[4];
      float wv[CW];
      #pragma unroll
      for (int i = 0; i < 4; ++i) a[i] = sA[ty * 4 + i][k];   // broadcast within lane groups
      #pragma unroll
      for (int h = 0; h < CW / 4; ++h) {
        float4 w4 = *reinterpret_cast<const float4*>(&sW[k][tx * 4 + 64 * h]);
        wv[h * 4 + 0] = w4.x; wv[h * 4 + 1] = w4.y; wv[h * 4 + 2] = w4.z; wv[h * 4 + 3] = w4.w;
      }
      #pragma unroll
      for (int i = 0; i < 4; ++i)
        #pragma unroll
        for (int j = 0; j < CW; ++j)
          acc[i][j] = fmaf(a[i], wv[j], acc[i][j]);
    }
  }
  // optional fused projections (raw acc, before activation — H1 gemm has none anyway)
  if (DO_PROJ) {
    float s4v[CW], n4v[CW];
    #pragma unroll
    for (int h = 0; h < CW / 4; ++h) {
      float4 s4 = *reinterpret_cast<const float4*>(a_s + tx * 4 + 64 * h);
      float4 n4 = *reinterpret_cast<const float4*>(a_n + tx * 4 + 64 * h);
      s4v[h*4+0]=s4.x; s4v[h*4+1]=s4.y; s4v[h*4+2]=s4.z; s4v[h*4+3]=s4.w;
      n4v[h*4+0]=n4.x; n4v[h*4+1]=n4.y; n4v[h*4+2]=n4.z; n4v[h*4+3]=n4.w;
    }
    #pragma unroll
    for (int i = 0; i < 4; ++i) {
      float ds = 0.f, dn = 0.f;
      #pragma unroll
      for (int j = 0; j < CW; ++j) { ds = fmaf(acc[i][j], s4v[j], ds); dn = fmaf(acc[i][j], n4v[j], dn); }
      #pragma unroll
      for (int o = 1; o < 16; o <<= 1) { ds += __shfl_xor(ds, o, 64); dn += __shfl_xor(dn, o, 64); }
      int gr = row0 + ty * 4 + i;
      if (tx == 0 && gr < M) { as_o[gr] = ds; an_o[gr] = dn; }
    }
  }
  // epilogue: cols for thread = tx*4 + 64*h, float4 stores
  #pragma unroll
  for (int i = 0; i < 4; ++i) {
    int gr = row0 + ty * 4 + i;
    if (gr >= M) continue;
    long rrow = 0;
    if (HAS_RES) rrow = ridx ? (long)ridx[gr] : (long)gr;
    #pragma unroll
    for (int h = 0; h < CW / 4; ++h) {
      int c = tx * 4 + 64 * h;
      float4 v = make_float4(acc[i][h*4+0], acc[i][h*4+1], acc[i][h*4+2], acc[i][h*4+3]);
      if (HAS_BIAS) {
        float4 bv = *reinterpret_cast<const float4*>(bias + c);
        v.x += bv.x; v.y += bv.y; v.z += bv.z; v.w += bv.w;
      }
      if (DO_ELU) {
        v.x = (v.x > 0.f) ? v.x : (__expf(v.x) - 1.f);
        v.y = (v.y > 0.f) ? v.y : (__expf(v.y) - 1.f);
        v.z = (v.z > 0.f) ? v.z : (__expf(v.z) - 1.f);
        v.w = (v.w > 0.f) ? v.w : (__expf(v.w) - 1.f);
      }
      if (HAS_RES) {
        float4 rv = *reinterpret_cast<const float4*>(Res + rrow * NC + c);
        v.x += rv.x; v.y += rv.y; v.z += rv.z; v.w += rv.w;
      }
      *reinterpret_cast<float4*>(C + (long)gr * NC + c) = v;
    }
  }
}

// ---------------- needed-dst flags (bytes) -------------
__global__ void flags_kernel(const int* __restrict__ ui, const int* __restrict__ ii, int B,
                             unsigned char* __restrict__ nfu, unsigned char* __restrict__ nfb)
{
  int i = blockIdx.x * blockDim.x + threadIdx.x;
  if (i < B) { nfu[ui[i]] = 1; nfb[ii[i]] = 1; }
}

// ---------------- pass 1: gated count + score + per-block dense append ----------
// rel = in-segment slot (counting-sort); entries packed {src, dst, rel, sc_bits}.
__global__ __launch_bounds__(256) void edge_prep(
    const int* __restrict__ src, const int* __restrict__ dst,
    const unsigned char* __restrict__ flag,
    const float* __restrict__ as_, const float* __restrict__ an_,
    const float* __restrict__ gc, const float* __restrict__ omega,
    int* __restrict__ deg, int4* __restrict__ cmp, int* __restrict__ blkcnt, int E)
{
  __shared__ int lcnt;
  if (threadIdx.x == 0) lcnt = 0;
  __syncthreads();
  int e = blockIdx.x * 256 + threadIdx.x;
  int lpos = -1; int4 entry;
  if (e < E) {
    int d = dst[e];
    if (flag[d]) {
      int s = src[e];
      float sc = as_[d] + an_[s];
      if (gc) {
        sc *= gc[(long)e*3+0]*omega[0] + gc[(long)e*3+1]*omega[1] + gc[(long)e*3+2]*omega[2];
      }
      sc = (sc >= 0.f) ? sc : 0.2f * sc;   // leaky_relu 0.2
      int rel = atomicAdd(&deg[d], 1);
      lpos = atomicAdd(&lcnt, 1);
      entry = make_int4(s, d, rel, __float_as_int(sc));
    }
  }
  if (lpos >= 0) cmp[(long)blockIdx.x * 256 + lpos] = entry;
  __syncthreads();
  if (threadIdx.x == 0) blkcnt[blockIdx.x] = lcnt;
}

// ---------------- pass 2: per-flagged-node compact slot + segment offsets ----------
__global__ __launch_bounds__(256) void offset_kernel(
    const unsigned char* __restrict__ flag, const int* __restrict__ deg,
    int* __restrict__ offs, int* __restrict__ dlist, int* __restrict__ g2c,
    int* __restrict__ cnt, int N)
{
  int i = blockIdx.x * 256 + threadIdx.x;
  if (i >= N || !flag[i]) return;
  int l = atomicAdd(&cnt[1], 1);
  g2c[i] = l;
  dlist[l] = i;
  int dg = deg[i];
  if (dg > 0) offs[i] = atomicAdd(&cnt[0], dg);
}

// ---------------- pass 3: place packed (src,sc) at offs[d]+rel — no atomics ----------
__global__ __launch_bounds__(256) void edge_place(
    const int4* __restrict__ cmp, const int* __restrict__ blkcnt,
    const int* __restrict__ offs, int2* __restrict__ eline)
{
  int nb = blkcnt[blockIdx.x];
  int t = threadIdx.x;
  if (t >= nb) return;
  int4 c = cmp[(long)blockIdx.x * 256 + t];
  int pos = offs[c.y] + c.z;
  eline[pos] = make_int2(c.x, c.w);
}

// ---------------- wave-per-dst softmax + aggregation (compact output) ----------
__global__ __launch_bounds__(256) void aggr_kernel(
    const int* __restrict__ dlist, const int* __restrict__ cnt,
    const int* __restrict__ offs, const int* __restrict__ deg,
    const int2* __restrict__ eline,
    const float* __restrict__ H1, float* __restrict__ Houtc)
{
  int wid  = (int)((blockIdx.x * 256 + threadIdx.x) >> 6);
  int lane = threadIdx.x & 63;
  if (wid >= cnt[1]) return;
  int d = dlist[wid];
  int n = deg[d];
  float2* op = reinterpret_cast<float2*>(Houtc + (long)wid * KD) + lane;
  if (n == 0) { *op = make_float2(0.f, 0.f); return; }
  int st = offs[d];
  // segment max
  float m = -3.4e38f;
  for (int i = lane; i < n; i += 64) m = fmaxf(m, __int_as_float(eline[st + i].y));
  #pragma unroll
  for (int o = 32; o; o >>= 1) m = fmaxf(m, __shfl_xor(m, o, 64));
  // segment sum of exp
  float s = 0.f;
  for (int i = lane; i < n; i += 64) s += __expf(__int_as_float(eline[st + i].y) - m);
  #pragma unroll
  for (int o = 32; o; o >>= 1) s += __shfl_xor(s, o, 64);
  float inv = 1.f / s;
  // weighted aggregation: each lane owns 2 columns; rows read coalesced
  float ax = 0.f, ay = 0.f;
  int i = 0;
  for (; i + 2 <= n; i += 2) {
    int2 e0 = eline[st + i], e1 = eline[st + i + 1];
    float a0 = __expf(__int_as_float(e0.y) - m);
    float a1 = __expf(__int_as_float(e1.y) - m);
    const float2 h0 = *reinterpret_cast<const float2*>(H1 + (long)e0.x * KD + lane * 2);
    const float2 h1 = *reinterpret_cast<const float2*>(H1 + (long)e1.x * KD + lane * 2);
    ax = fmaf(h0.x, a0, ax); ay = fmaf(h0.y, a0, ay);
    ax = fmaf(h1.x, a1, ax); ay = fmaf(h1.y, a1, ay);
  }
  if (i < n) {
    int2 e0 = eline[st + i];
    float a0 = __expf(__int_as_float(e0.y) - m);
    const float2 h0 = *reinterpret_cast<const float2*>(H1 + (long)e0.x * KD + lane * 2);
    ax = fmaf(h0.x, a0, ax); ay = fmaf(h0.y, a0, ay);
  }
  *op = make_float2(ax * inv, ay * inv);
}

// ---------------- final: dot + biases + sigmoid -------------
__global__ __launch_bounds__(256) void final_kernel(
    const float* __restrict__ Ug, const float* __restrict__ Bg,
    const int* __restrict__ ui, const int* __restrict__ ii,
    const float* __restrict__ bias_u, const float* __restrict__ bias_b,
    const float* __restrict__ bx, float* __restrict__ out, int B)
{
  int wid  = (int)((blockIdx.x * 256 + threadIdx.x) >> 6);
  int lane = threadIdx.x & 63;
  if (wid >= B) return;
  float v = Ug[(long)wid * 64 + lane] * Bg[(long)wid * 64 + lane];
  #pragma unroll
  for (int o = 32; o > 0; o >>= 1) v += __shfl_xor(v, o, 64);
  if (lane == 0) {
    float raw = v + bias_u[ui[wid]] + bias_b[ii[wid]] + bx[0];
    out[wid] = 4.f / (1.f + __expf(-raw)) + 1.f;
  }
}

extern "C" void kernel_launch(void* const* d_in, const int* in_sizes, int n_in,
                              void* d_out, int out_size, void* d_ws, size_t ws_size,
                              hipStream_t stream)
{
  const int*   ui    = (const int*)  d_in[0];
  const int*   ii    = (const int*)  d_in[1];
  const float* S_u   = (const float*)d_in[2];
  const float* S_b   = (const float*)d_in[3];
  const int*   eu    = (const int*)  d_in[4];
  const int*   eb    = (const int*)  d_in[5];
  const float* gc    = (const float*)d_in[6];
  const float* W1_u  = (const float*)d_in[7];
  const float* a_s_u = (const float*)d_in[8];
  const float* a_n_u = (const float*)d_in[9];
  const float* W1_b  = (const float*)d_in[10];
  const float* a_s_b = (const float*)d_in[11];
  const float* a_n_b = (const float*)d_in[12];
  const float* omega = (const float*)d_in[13];
  const float* W_u2  = (const float*)d_in[14];
  const float* W_us2w= (const float*)d_in[15];
  const float* W_us2b= (const float*)d_in[16];
  const float* W_b2  = (const float*)d_in[17];
  const float* W_bs2w= (const float*)d_in[18];
  const float* W_bs2b= (const float*)d_in[19];
  const float* W_u3  = (const float*)d_in[20];
  const float* W_b3  = (const float*)d_in[21];
  const float* H_u4  = (const float*)d_in[22];
  const float* H_b4  = (const float*)d_in[23];
  const float* bias_u= (const float*)d_in[24];
  const float* bias_b= (const float*)d_in[25];
  const float* b_x   = (const float*)d_in[26];
  float* out = (float*)d_out;

  const int B  = in_sizes[0];
  const int NU = in_sizes[2] / KD;
  const int NI = in_sizes[3] / KD;
  const int EU = in_sizes[4] / 2;
  const int EB = in_sizes[5] / 2;
  const int GPU_ = (EU + 255) / 256;   // edge_prep grids
  const int GPB_ = (EB + 255) / 256;

  char* w = (char*)d_ws;
  auto alloc = [&](size_t bytes) -> void* {
    void* r = (void*)w;
    w += (bytes + 255) & ~(size_t)255;
    return r;
  };
  // ---- zero-initialized region (one small memset per call) ----
  int* deg_u = (int*)alloc((size_t)NU * 4);
  int* deg_b = (int*)alloc((size_t)NI * 4);
  unsigned char* nfu = (unsigned char*)alloc((size_t)NU);
  unsigned char* nfb = (unsigned char*)alloc((size_t)NI);
  int* cnt   = (int*)alloc(16 * 4);          // [0,1]=user {edges,dsts}, [2,3]=item
  size_t zbytes = (size_t)(w - (char*)d_ws);
  // ---- scratch (fully written before read each call) ----
  int*   offs_u = (int*)  alloc((size_t)NU * 4);
  int*   offs_b = (int*)  alloc((size_t)NI * 4);
  int*   g2c_u  = (int*)  alloc((size_t)NU * 4);
  int*   g2c_b  = (int*)  alloc((size_t)NI * 4);
  int*   dl_u   = (int*)  alloc((size_t)B * 4);
  int*   dl_b   = (int*)  alloc((size_t)B * 4);
  int*   bc_u   = (int*)  alloc((size_t)GPU_ * 4);
  int*   bc_b   = (int*)  alloc((size_t)GPB_ * 4);
  int4*  cmp_u  = (int4*) alloc((size_t)GPU_ * 256 * 16);
  int4*  cmp_b  = (int4*) alloc((size_t)GPB_ * 256 * 16);
  int2*  el_u   = (int2*) alloc((size_t)EU * 8);
  int2*  el_b   = (int2*) alloc((size_t)EB * 8);
  float* H1u  = (float*)alloc((size_t)NU * KD * 4);
  float* H1b  = (float*)alloc((size_t)NI * KD * 4);
  float* Hu2c = (float*)alloc((size_t)B * KD * 4);
  float* Hb2c = (float*)alloc((size_t)B * KD * 4);
  float* asu  = (float*)alloc((size_t)NU * 4);
  float* anu  = (float*)alloc((size_t)NU * 4);
  float* asb  = (float*)alloc((size_t)NI * 4);
  float* anb  = (float*)alloc((size_t)NI * 4);
  float* Hu3g = (float*)alloc((size_t)B * KD * 4);
  float* Hb3g = (float*)alloc((size_t)B * KD * 4);
  float* Ug   = (float*)alloc((size_t)B * 64 * 4);
  float* Bg   = (float*)alloc((size_t)B * 64 * 4);
  (void)ws_size; (void)n_in; (void)out_size;

  hipMemsetAsync(d_ws, 0, zbytes, stream);

  flags_kernel<<<(B + 255) / 256, 256, 0, stream>>>(ui, ii, B, nfu, nfb);

  // H1 = S @ W1, with fused per-row projections as/an
  gemm_k128<128,false,false,false,false,true><<<(NU + 63) / 64, 256, 0, stream>>>(
      S_u, W1_u, nullptr, nullptr, nullptr, nullptr, nullptr, nullptr, nullptr,
      NU, H1u, a_s_u, a_n_u, asu, anu);
  gemm_k128<128,false,false,false,false,true><<<(NI + 63) / 64, 256, 0, stream>>>(
      S_b, W1_b, nullptr, nullptr, nullptr, nullptr, nullptr, nullptr, nullptr,
      NI, H1b, a_s_b, a_n_b, asb, anb);

  edge_prep<<<GPU_, 256, 0, stream>>>(eu, eu + EU, nfu, asu, anu, nullptr, nullptr,
                                      deg_u, cmp_u, bc_u, EU);
  edge_prep<<<GPB_, 256, 0, stream>>>(eb, eb + EB, nfb, asb, anb, gc, omega,
                                      deg_b, cmp_b, bc_b, EB);

  offset_kernel<<<(NU + 255) / 256, 256, 0, stream>>>(nfu, deg_u, offs_u, dl_u, g2c_u, cnt + 0, NU);
  offset_kernel<<<(NI + 255) / 256, 256, 0, stream>>>(nfb, deg_b, offs_b, dl_b, g2c_b, cnt + 2, NI);

  edge_place<<<GPU_, 256, 0, stream>>>(cmp_u, bc_u, offs_u, el_u);
  edge_place<<<GPB_, 256, 0, stream>>>(cmp_b, bc_b, offs_b, el_b);

  aggr_kernel<<<(B * 64 + 255) / 256, 256, 0, stream>>>(dl_u, cnt + 0, offs_u, deg_u, el_u, H1u, Hu2c);
  aggr_kernel<<<(B * 64 + 255) / 256, 256, 0, stream>>>(dl_b, cnt + 2, offs_b, deg_b, el_b, H1b, Hb2c);

  // Hu3 = elu(Hu2c[g2c[ui]] @ W_u2 + S_u[ui] @ W_us2 + b)
  gemm_k128<128,true,true,true,false,false><<<(B + 63) / 64, 256, 0, stream>>>(
      Hu2c, W_u2, S_u, W_us2w, W_us2b, nullptr, ui, g2c_u, nullptr,
      B, Hu3g, nullptr, nullptr, nullptr, nullptr);
  gemm_k128<128,true,true,true,false,false><<<(B + 63) / 64, 256, 0, stream>>>(
      Hb2c, W_b2, S_b, W_bs2w, W_bs2b, nullptr, ii, g2c_b, nullptr,
      B, Hb3g, nullptr, nullptr, nullptr, nullptr);

  // U = elu(Hu3 @ W_u3) + H_u4[ui]
  gemm_k128<64,false,false,true,true,false><<<(B + 63) / 64, 256, 0, stream>>>(
      Hu3g, W_u3, nullptr, nullptr, nullptr, H_u4, nullptr, nullptr, ui,
      B, Ug, nullptr, nullptr, nullptr, nullptr);
  gemm_k128<64,false,false,true,true,false><<<(B + 63) / 64, 256, 0, stream>>>(
      Hb3g, W_b3, nullptr, nullptr, nullptr, H_b4, nullptr, nullptr, ii,
      B, Bg, nullptr, nullptr, nullptr, nullptr);

  final_kernel<<<(B + 3) / 4, 256, 0, stream>>>(Ug, Bg, ui, ii, bias_u, bias_b, b_x, out, B);
}

// Round 6
// 428.126 us; speedup vs baseline: 4.8835x; 1.0563x over previous
//
#include <hip/hip_runtime.h>
#include <hip/hip_bf16.h>

#define KD 128

// ---------------- generic K=128 GEMM: C = act(A1[map1[idx]]@W1 (+A2[idx]@W2) (+bias)) (+Res[ridx])
// Optional fused projections: as_o = row@a_s, an_o = row@a_n (for the H1 GAT gemm).
// 64 rows/block, NC cols, 256 threads, thread tile 4x(NC/16). K chunked at KB=64,
// single-buffered LDS (stage -> barrier -> compute -> barrier). ~49KB LDS -> 3 blocks/CU.
template<int NC, bool HAS_A2, bool HAS_BIAS, bool DO_ELU, bool HAS_RES, bool DO_PROJ>
__global__ __launch_bounds__(256, 3) void gemm_k128(
    const float* __restrict__ A1, const float* __restrict__ W1,
    const float* __restrict__ A2, const float* __restrict__ W2,
    const float* __restrict__ bias, const float* __restrict__ Res,
    const int* __restrict__ aidx, const int* __restrict__ map1,
    const int* __restrict__ ridx,
    int M, float* __restrict__ C,
    const float* __restrict__ a_s, const float* __restrict__ a_n,
    float* __restrict__ as_o, float* __restrict__ an_o)
{
  constexpr int CW = NC / 16;            // cols per thread (8 for NC=128, 4 for NC=64)
  constexpr int KB = 64;                 // K chunk
  constexpr int NAF4 = 64 * KB / 4 / 256;   // A float4s per thread per chunk (4)
  constexpr int NWF4 = KB * NC / 4 / 256;   // W float4s per thread per chunk (8 or 4)
  __shared__ float sA[64][KB + 4];       // row stride 68 floats
  __shared__ float sW[KB][NC];
  const int t  = threadIdx.x;
  const int ty = t >> 4, tx = t & 15;
  const int row0 = blockIdx.x * 64;

  float acc[4][CW];
  #pragma unroll
  for (int i = 0; i < 4; ++i)
    #pragma unroll
    for (int j = 0; j < CW; ++j) acc[i][j] = 0.f;

  const int npass = HAS_A2 ? 2 : 1;
  const int NCH = npass * (KD / KB);     // 2 chunks per pass

  for (int cc = 0; cc < NCH; ++cc) {
    const float* Am = (cc < 2) ? A1 : A2;
    const float* Wm = (cc < 2) ? W1 : W2;
    const int* mp   = (cc < 2) ? map1 : nullptr;
    const int kc = cc & 1;               // K chunk index within pass
    if (cc) __syncthreads();             // previous compute done before overwrite
    // stage W chunk: rows [kc*KB, kc*KB+KB) x NC, linear float4, coalesced
    {
      const float4* Wp = reinterpret_cast<const float4*>(Wm) + (long)kc * (KB * NC / 4);
      #pragma unroll
      for (int q = 0; q < NWF4; ++q)
        reinterpret_cast<float4*>(&sW[0][0])[t + 256 * q] = Wp[t + 256 * q];
    }
    // stage A chunk: 64 rows x KB cols, row-major, coalesced 16 lanes/row
    #pragma unroll
    for (int q = 0; q < NAF4; ++q) {
      int p  = t + 256 * q;
      int r  = p >> 4, c4 = p & 15;
      float4 v = make_float4(0.f, 0.f, 0.f, 0.f);
      int gr = row0 + r;
      if (gr < M) {
        long grow = aidx ? (long)aidx[gr] : (long)gr;
        if (mp) grow = mp[grow];
        v = reinterpret_cast<const float4*>(Am + grow * KD)[kc * (KB / 4) + c4];
      }
      *reinterpret_cast<float4*>(&sA[r][c4 * 4]) = v;
    }
    __syncthreads();
    #pragma unroll 4
    for (int k = 0; k < KB; ++k) {
      float a[4];
      float wv[CW];
      #pragma unroll
      for (int i = 0; i < 4; ++i) a[i] = sA[ty * 4 + i][k];   // broadcast within lane groups
      #pragma unroll
      for (int h = 0; h < CW / 4; ++h) {
        float4 w4 = *reinterpret_cast<const float4*>(&sW[k][tx * 4 + 64 * h]);
        wv[h * 4 + 0] = w4.x; wv[h * 4 + 1] = w4.y; wv[h * 4 + 2] = w4.z; wv[h * 4 + 3] = w4.w;
      }
      #pragma unroll
      for (int i = 0; i < 4; ++i)
        #pragma unroll
        for (int j = 0; j < CW; ++j)
          acc[i][j] = fmaf(a[i], wv[j], acc[i][j]);
    }
  }
  // optional fused projections (raw acc, before activation — H1 gemm has none anyway)
  if (DO_PROJ) {
    float s4v[CW], n4v[CW];
    #pragma unroll
    for (int h = 0; h < CW / 4; ++h) {
      float4 s4 = *reinterpret_cast<const float4*>(a_s + tx * 4 + 64 * h);
      float4 n4 = *reinterpret_cast<const float4*>(a_n + tx * 4 + 64 * h);
      s4v[h*4+0]=s4.x; s4v[h*4+1]=s4.y; s4v[h*4+2]=s4.z; s4v[h*4+3]=s4.w;
      n4v[h*4+0]=n4.x; n4v[h*4+1]=n4.y; n4v[h*4+2]=n4.z; n4v[h*4+3]=n4.w;
    }
    #pragma unroll
    for (int i = 0; i < 4; ++i) {
      float ds = 0.f, dn = 0.f;
      #pragma unroll
      for (int j = 0; j < CW; ++j) { ds = fmaf(acc[i][j], s4v[j], ds); dn = fmaf(acc[i][j], n4v[j], dn); }
      #pragma unroll
      for (int o = 1; o < 16; o <<= 1) { ds += __shfl_xor(ds, o, 64); dn += __shfl_xor(dn, o, 64); }
      int gr = row0 + ty * 4 + i;
      if (tx == 0 && gr < M) { as_o[gr] = ds; an_o[gr] = dn; }
    }
  }
  // epilogue: cols for thread = tx*4 + 64*h, float4 stores
  #pragma unroll
  for (int i = 0; i < 4; ++i) {
    int gr = row0 + ty * 4 + i;
    if (gr >= M) continue;
    long rrow = 0;
    if (HAS_RES) rrow = ridx ? (long)ridx[gr] : (long)gr;
    #pragma unroll
    for (int h = 0; h < CW / 4; ++h) {
      int c = tx * 4 + 64 * h;
      float4 v = make_float4(acc[i][h*4+0], acc[i][h*4+1], acc[i][h*4+2], acc[i][h*4+3]);
      if (HAS_BIAS) {
        float4 bv = *reinterpret_cast<const float4*>(bias + c);
        v.x += bv.x; v.y += bv.y; v.z += bv.z; v.w += bv.w;
      }
      if (DO_ELU) {
        v.x = (v.x > 0.f) ? v.x : (__expf(v.x) - 1.f);
        v.y = (v.y > 0.f) ? v.y : (__expf(v.y) - 1.f);
        v.z = (v.z > 0.f) ? v.z : (__expf(v.z) - 1.f);
        v.w = (v.w > 0.f) ? v.w : (__expf(v.w) - 1.f);
      }
      if (HAS_RES) {
        float4 rv = *reinterpret_cast<const float4*>(Res + rrow * NC + c);
        v.x += rv.x; v.y += rv.y; v.z += rv.z; v.w += rv.w;
      }
      *reinterpret_cast<float4*>(C + (long)gr * NC + c) = v;
    }
  }
}

// ---------------- needed-dst flags (bytes) -------------
__global__ void flags_kernel(const int* __restrict__ ui, const int* __restrict__ ii, int B,
                             unsigned char* __restrict__ nfu, unsigned char* __restrict__ nfb)
{
  int i = blockIdx.x * blockDim.x + threadIdx.x;
  if (i < B) { nfu[ui[i]] = 1; nfb[ii[i]] = 1; }
}

// ---------------- pass 1: gated count + score + per-block dense append ----------
// 4 edges/thread (int4 loads -> 4 independent gathers in flight), ballot compaction
// (1 LDS atomic per wave per sub-edge instead of 1 per lane).
// rel = in-segment slot (counting-sort); entries packed {src, dst, rel, sc_bits}.
__global__ __launch_bounds__(256) void edge_prep(
    const int* __restrict__ src, const int* __restrict__ dst,
    const unsigned char* __restrict__ flag,
    const float* __restrict__ as_, const float* __restrict__ an_,
    const float* __restrict__ gc, const float* __restrict__ omega,
    int* __restrict__ deg, int4* __restrict__ cmp, int* __restrict__ blkcnt, int E)
{
  __shared__ int lcnt;
  if (threadIdx.x == 0) lcnt = 0;
  __syncthreads();
  const int lane = threadIdx.x & 63;
  const long base = (long)blockIdx.x * 1024;
  const int e0 = (int)base + threadIdx.x * 4;

  int d[4], s[4];
  bool act[4];
  if (e0 + 3 < E) {
    int4 d4 = *reinterpret_cast<const int4*>(dst + e0);
    int4 s4 = *reinterpret_cast<const int4*>(src + e0);
    d[0]=d4.x; d[1]=d4.y; d[2]=d4.z; d[3]=d4.w;
    s[0]=s4.x; s[1]=s4.y; s[2]=s4.z; s[3]=s4.w;
    #pragma unroll
    for (int j = 0; j < 4; ++j) act[j] = true;
  } else {
    #pragma unroll
    for (int j = 0; j < 4; ++j) {
      act[j] = (e0 + j < E);
      d[j] = act[j] ? dst[e0 + j] : 0;
      s[j] = act[j] ? src[e0 + j] : 0;
    }
  }
  // independent flag gathers
  #pragma unroll
  for (int j = 0; j < 4; ++j) if (act[j]) act[j] = (flag[d[j]] != 0);
  // scores (independent gathers for active)
  float sc[4];
  #pragma unroll
  for (int j = 0; j < 4; ++j) {
    float v = 0.f;
    if (act[j]) {
      v = as_[d[j]] + an_[s[j]];
      if (gc) {
        long e = e0 + j;
        v *= gc[e*3+0]*omega[0] + gc[e*3+1]*omega[1] + gc[e*3+2]*omega[2];
      }
      v = (v >= 0.f) ? v : 0.2f * v;     // leaky_relu 0.2
    }
    sc[j] = v;
  }
  // per-sub-edge ballot compaction
  #pragma unroll
  for (int j = 0; j < 4; ++j) {
    unsigned long long m = __ballot(act[j]);
    int nw = __popcll(m);
    if (nw == 0) continue;
    int pref = __popcll(m & ((1ull << lane) - 1ull));
    int wb = 0;
    if (lane == 0) wb = atomicAdd(&lcnt, nw);
    wb = __shfl(wb, 0, 64);
    if (act[j]) {
      int rel = atomicAdd(&deg[d[j]], 1);
      cmp[base + wb + pref] = make_int4(s[j], d[j], rel, __float_as_int(sc[j]));
    }
  }
  __syncthreads();
  if (threadIdx.x == 0) blkcnt[blockIdx.x] = lcnt;
}

// ---------------- pass 2: per-flagged-node compact slot + segment offsets ----------
__global__ __launch_bounds__(256) void offset_kernel(
    const unsigned char* __restrict__ flag, const int* __restrict__ deg,
    int* __restrict__ offs, int* __restrict__ dlist, int* __restrict__ g2c,
    int* __restrict__ cnt, int N)
{
  int i = blockIdx.x * 256 + threadIdx.x;
  if (i >= N || !flag[i]) return;
  int l = atomicAdd(&cnt[1], 1);
  g2c[i] = l;
  dlist[l] = i;
  int dg = deg[i];
  if (dg > 0) offs[i] = atomicAdd(&cnt[0], dg);
}

// ---------------- pass 3: place packed (src,sc) at offs[d]+rel — no atomics ----------
__global__ __launch_bounds__(256) void edge_place(
    const int4* __restrict__ cmp, const int* __restrict__ blkcnt,
    const int* __restrict__ offs, int2* __restrict__ eline)
{
  int nb = blkcnt[blockIdx.x];
  const long base = (long)blockIdx.x * 1024;
  for (int k = threadIdx.x; k < nb; k += 256) {
    int4 c = cmp[base + k];
    int pos = offs[c.y] + c.z;
    eline[pos] = make_int2(c.x, c.w);
  }
}

// ---------------- wave-per-dst softmax + aggregation (compact output) ----------
__global__ __launch_bounds__(256) void aggr_kernel(
    const int* __restrict__ dlist, const int* __restrict__ cnt,
    const int* __restrict__ offs, const int* __restrict__ deg,
    const int2* __restrict__ eline,
    const float* __restrict__ H1, float* __restrict__ Houtc)
{
  int wid  = (int)((blockIdx.x * 256 + threadIdx.x) >> 6);
  int lane = threadIdx.x & 63;
  if (wid >= cnt[1]) return;
  int d = dlist[wid];
  int n = deg[d];
  float2* op = reinterpret_cast<float2*>(Houtc + (long)wid * KD) + lane;
  if (n == 0) { *op = make_float2(0.f, 0.f); return; }
  int st = offs[d];
  // segment max
  float m = -3.4e38f;
  for (int i = lane; i < n; i += 64) m = fmaxf(m, __int_as_float(eline[st + i].y));
  #pragma unroll
  for (int o = 32; o; o >>= 1) m = fmaxf(m, __shfl_xor(m, o, 64));
  // segment sum of exp
  float s = 0.f;
  for (int i = lane; i < n; i += 64) s += __expf(__int_as_float(eline[st + i].y) - m);
  #pragma unroll
  for (int o = 32; o; o >>= 1) s += __shfl_xor(s, o, 64);
  float inv = 1.f / s;
  // weighted aggregation: each lane owns 2 columns; rows read coalesced
  float ax = 0.f, ay = 0.f;
  int i = 0;
  for (; i + 2 <= n; i += 2) {
    int2 e0 = eline[st + i], e1 = eline[st + i + 1];
    float a0 = __expf(__int_as_float(e0.y) - m);
    float a1 = __expf(__int_as_float(e1.y) - m);
    const float2 h0 = *reinterpret_cast<const float2*>(H1 + (long)e0.x * KD + lane * 2);
    const float2 h1 = *reinterpret_cast<const float2*>(H1 + (long)e1.x * KD + lane * 2);
    ax = fmaf(h0.x, a0, ax); ay = fmaf(h0.y, a0, ay);
    ax = fmaf(h1.x, a1, ax); ay = fmaf(h1.y, a1, ay);
  }
  if (i < n) {
    int2 e0 = eline[st + i];
    float a0 = __expf(__int_as_float(e0.y) - m);
    const float2 h0 = *reinterpret_cast<const float2*>(H1 + (long)e0.x * KD + lane * 2);
    ax = fmaf(h0.x, a0, ax); ay = fmaf(h0.y, a0, ay);
  }
  *op = make_float2(ax * inv, ay * inv);
}

// ---------------- final: dot + biases + sigmoid -------------
__global__ __launch_bounds__(256) void final_kernel(
    const float* __restrict__ Ug, const float* __restrict__ Bg,
    const int* __restrict__ ui, const int* __restrict__ ii,
    const float* __restrict__ bias_u, const float* __restrict__ bias_b,
    const float* __restrict__ bx, float* __restrict__ out, int B)
{
  int wid  = (int)((blockIdx.x * 256 + threadIdx.x) >> 6);
  int lane = threadIdx.x & 63;
  if (wid >= B) return;
  float v = Ug[(long)wid * 64 + lane] * Bg[(long)wid * 64 + lane];
  #pragma unroll
  for (int o = 32; o > 0; o >>= 1) v += __shfl_xor(v, o, 64);
  if (lane == 0) {
    float raw = v + bias_u[ui[wid]] + bias_b[ii[wid]] + bx[0];
    out[wid] = 4.f / (1.f + __expf(-raw)) + 1.f;
  }
}

extern "C" void kernel_launch(void* const* d_in, const int* in_sizes, int n_in,
                              void* d_out, int out_size, void* d_ws, size_t ws_size,
                              hipStream_t stream)
{
  const int*   ui    = (const int*)  d_in[0];
  const int*   ii    = (const int*)  d_in[1];
  const float* S_u   = (const float*)d_in[2];
  const float* S_b   = (const float*)d_in[3];
  const int*   eu    = (const int*)  d_in[4];
  const int*   eb    = (const int*)  d_in[5];
  const float* gc    = (const float*)d_in[6];
  const float* W1_u  = (const float*)d_in[7];
  const float* a_s_u = (const float*)d_in[8];
  const float* a_n_u = (const float*)d_in[9];
  const float* W1_b  = (const float*)d_in[10];
  const float* a_s_b = (const float*)d_in[11];
  const float* a_n_b = (const float*)d_in[12];
  const float* omega = (const float*)d_in[13];
  const float* W_u2  = (const float*)d_in[14];
  const float* W_us2w= (const float*)d_in[15];
  const float* W_us2b= (const float*)d_in[16];
  const float* W_b2  = (const float*)d_in[17];
  const float* W_bs2w= (const float*)d_in[18];
  const float* W_bs2b= (const float*)d_in[19];
  const float* W_u3  = (const float*)d_in[20];
  const float* W_b3  = (const float*)d_in[21];
  const float* H_u4  = (const float*)d_in[22];
  const float* H_b4  = (const float*)d_in[23];
  const float* bias_u= (const float*)d_in[24];
  const float* bias_b= (const float*)d_in[25];
  const float* b_x   = (const float*)d_in[26];
  float* out = (float*)d_out;

  const int B  = in_sizes[0];
  const int NU = in_sizes[2] / KD;
  const int NI = in_sizes[3] / KD;
  const int EU = in_sizes[4] / 2;
  const int EB = in_sizes[5] / 2;
  const int GPU_ = (EU + 1023) / 1024;   // edge_prep grids (1024 edges/block)
  const int GPB_ = (EB + 1023) / 1024;

  char* w = (char*)d_ws;
  auto alloc = [&](size_t bytes) -> void* {
    void* r = (void*)w;
    w += (bytes + 255) & ~(size_t)255;
    return r;
  };
  // ---- zero-initialized region (one small memset per call) ----
  int* deg_u = (int*)alloc((size_t)NU * 4);
  int* deg_b = (int*)alloc((size_t)NI * 4);
  unsigned char* nfu = (unsigned char*)alloc((size_t)NU);
  unsigned char* nfb = (unsigned char*)alloc((size_t)NI);
  int* cnt   = (int*)alloc(16 * 4);          // [0,1]=user {edges,dsts}, [2,3]=item
  size_t zbytes = (size_t)(w - (char*)d_ws);
  // ---- scratch (fully written before read each call) ----
  int*   offs_u = (int*)  alloc((size_t)NU * 4);
  int*   offs_b = (int*)  alloc((size_t)NI * 4);
  int*   g2c_u  = (int*)  alloc((size_t)NU * 4);
  int*   g2c_b  = (int*)  alloc((size_t)NI * 4);
  int*   dl_u   = (int*)  alloc((size_t)B * 4);
  int*   dl_b   = (int*)  alloc((size_t)B * 4);
  int*   bc_u   = (int*)  alloc((size_t)GPU_ * 4);
  int*   bc_b   = (int*)  alloc((size_t)GPB_ * 4);
  int4*  cmp_u  = (int4*) alloc((size_t)GPU_ * 1024 * 16);
  int4*  cmp_b  = (int4*) alloc((size_t)GPB_ * 1024 * 16);
  int2*  el_u   = (int2*) alloc((size_t)EU * 8);
  int2*  el_b   = (int2*) alloc((size_t)EB * 8);
  float* H1u  = (float*)alloc((size_t)NU * KD * 4);
  float* H1b  = (float*)alloc((size_t)NI * KD * 4);
  float* Hu2c = (float*)alloc((size_t)B * KD * 4);
  float* Hb2c = (float*)alloc((size_t)B * KD * 4);
  float* asu  = (float*)alloc((size_t)NU * 4);
  float* anu  = (float*)alloc((size_t)NU * 4);
  float* asb  = (float*)alloc((size_t)NI * 4);
  float* anb  = (float*)alloc((size_t)NI * 4);
  float* Hu3g = (float*)alloc((size_t)B * KD * 4);
  float* Hb3g = (float*)alloc((size_t)B * KD * 4);
  float* Ug   = (float*)alloc((size_t)B * 64 * 4);
  float* Bg   = (float*)alloc((size_t)B * 64 * 4);
  (void)ws_size; (void)n_in; (void)out_size;

  hipMemsetAsync(d_ws, 0, zbytes, stream);

  flags_kernel<<<(B + 255) / 256, 256, 0, stream>>>(ui, ii, B, nfu, nfb);

  // H1 = S @ W1, with fused per-row projections as/an
  gemm_k128<128,false,false,false,false,true><<<(NU + 63) / 64, 256, 0, stream>>>(
      S_u, W1_u, nullptr, nullptr, nullptr, nullptr, nullptr, nullptr, nullptr,
      NU, H1u, a_s_u, a_n_u, asu, anu);
  gemm_k128<128,false,false,false,false,true><<<(NI + 63) / 64, 256, 0, stream>>>(
      S_b, W1_b, nullptr, nullptr, nullptr, nullptr, nullptr, nullptr, nullptr,
      NI, H1b, a_s_b, a_n_b, asb, anb);

  edge_prep<<<GPU_, 256, 0, stream>>>(eu, eu + EU, nfu, asu, anu, nullptr, nullptr,
                                      deg_u, cmp_u, bc_u, EU);
  edge_prep<<<GPB_, 256, 0, stream>>>(eb, eb + EB, nfb, asb, anb, gc, omega,
                                      deg_b, cmp_b, bc_b, EB);

  offset_kernel<<<(NU + 255) / 256, 256, 0, stream>>>(nfu, deg_u, offs_u, dl_u, g2c_u, cnt + 0, NU);
  offset_kernel<<<(NI + 255) / 256, 256, 0, stream>>>(nfb, deg_b, offs_b, dl_b, g2c_b, cnt + 2, NI);

  edge_place<<<GPU_, 256, 0, stream>>>(cmp_u, bc_u, offs_u, el_u);
  edge_place<<<GPB_, 256, 0, stream>>>(cmp_b, bc_b, offs_b, el_b);

  aggr_kernel<<<(B * 64 + 255) / 256, 256, 0, stream>>>(dl_u, cnt + 0, offs_u, deg_u, el_u, H1u, Hu2c);
  aggr_kernel<<<(B * 64 + 255) / 256, 256, 0, stream>>>(dl_b, cnt + 2, offs_b, deg_b, el_b, H1b, Hb2c);

  // Hu3 = elu(Hu2c[g2c[ui]] @ W_u2 + S_u[ui] @ W_us2 + b)
  gemm_k128<128,true,true,true,false,false><<<(B + 63) / 64, 256, 0, stream>>>(
      Hu2c, W_u2, S_u, W_us2w, W_us2b, nullptr, ui, g2c_u, nullptr,
      B, Hu3g, nullptr, nullptr, nullptr, nullptr);
  gemm_k128<128,true,true,true,false,false><<<(B + 63) / 64, 256, 0, stream>>>(
      Hb2c, W_b2, S_b, W_bs2w, W_bs2b, nullptr, ii, g2c_b, nullptr,
      B, Hb3g, nullptr, nullptr, nullptr, nullptr);

  // U = elu(Hu3 @ W_u3) + H_u4[ui]
  gemm_k128<64,false,false,true,true,false><<<(B + 63) / 64, 256, 0, stream>>>(
      Hu3g, W_u3, nullptr, nullptr, nullptr, H_u4, nullptr, nullptr, ui,
      B, Ug, nullptr, nullptr, nullptr, nullptr);
  gemm_k128<64,false,false,true,true,false><<<(B + 63) / 64, 256, 0, stream>>>(
      Hb3g, W_b3, nullptr, nullptr, nullptr, H_b4, nullptr, nullptr, ii,
      B, Bg, nullptr, nullptr, nullptr, nullptr);

  final_kernel<<<(B + 3) / 4, 256, 0, stream>>>(Ug, Bg, ui, ii, bias_u, bias_b, b_x, out, B);
}

// Round 7
// 417.654 us; speedup vs baseline: 5.0060x; 1.0251x over previous
//
#include <hip/hip_runtime.h>
#include <hip/hip_bf16.h>

#define KD 128

// ---------------- generic K=128 GEMM: C = act(A1[map1[idx]]@W1 (+A2[idx]@W2) (+bias)) (+Res[ridx])
// Optional fused projections: as_o = row@a_s, an_o = row@a_n (for the H1 GAT gemm).
// 64 rows/block, NC cols, 256 threads, thread tile 4x(NC/16). K chunked at KB=64,
// single-buffered LDS (stage -> barrier -> compute -> barrier). ~49KB LDS -> 3 blocks/CU.
template<int NC, bool HAS_A2, bool HAS_BIAS, bool DO_ELU, bool HAS_RES, bool DO_PROJ>
__global__ __launch_bounds__(256, 3) void gemm_k128(
    const float* __restrict__ A1, const float* __restrict__ W1,
    const float* __restrict__ A2, const float* __restrict__ W2,
    const float* __restrict__ bias, const float* __restrict__ Res,
    const int* __restrict__ aidx, const int* __restrict__ map1,
    const int* __restrict__ ridx,
    int M, float* __restrict__ C,
    const float* __restrict__ a_s, const float* __restrict__ a_n,
    float* __restrict__ as_o, float* __restrict__ an_o)
{
  constexpr int CW = NC / 16;            // cols per thread (8 for NC=128, 4 for NC=64)
  constexpr int KB = 64;                 // K chunk
  constexpr int NAF4 = 64 * KB / 4 / 256;   // A float4s per thread per chunk (4)
  constexpr int NWF4 = KB * NC / 4 / 256;   // W float4s per thread per chunk (8 or 4)
  __shared__ float sA[64][KB + 4];       // row stride 68 floats
  __shared__ float sW[KB][NC];
  const int t  = threadIdx.x;
  const int ty = t >> 4, tx = t & 15;
  const int row0 = blockIdx.x * 64;

  float acc[4][CW];
  #pragma unroll
  for (int i = 0; i < 4; ++i)
    #pragma unroll
    for (int j = 0; j < CW; ++j) acc[i][j] = 0.f;

  const int npass = HAS_A2 ? 2 : 1;
  const int NCH = npass * (KD / KB);     // 2 chunks per pass

  for (int cc = 0; cc < NCH; ++cc) {
    const float* Am = (cc < 2) ? A1 : A2;
    const float* Wm = (cc < 2) ? W1 : W2;
    const int* mp   = (cc < 2) ? map1 : nullptr;
    const int kc = cc & 1;               // K chunk index within pass
    if (cc) __syncthreads();             // previous compute done before overwrite
    // stage W chunk: rows [kc*KB, kc*KB+KB) x NC, linear float4, coalesced
    {
      const float4* Wp = reinterpret_cast<const float4*>(Wm) + (long)kc * (KB * NC / 4);
      #pragma unroll
      for (int q = 0; q < NWF4; ++q)
        reinterpret_cast<float4*>(&sW[0][0])[t + 256 * q] = Wp[t + 256 * q];
    }
    // stage A chunk: 64 rows x KB cols, row-major, coalesced 16 lanes/row
    #pragma unroll
    for (int q = 0; q < NAF4; ++q) {
      int p  = t + 256 * q;
      int r  = p >> 4, c4 = p & 15;
      float4 v = make_float4(0.f, 0.f, 0.f, 0.f);
      int gr = row0 + r;
      if (gr < M) {
        long grow = aidx ? (long)aidx[gr] : (long)gr;
        if (mp) grow = mp[grow];
        v = reinterpret_cast<const float4*>(Am + grow * KD)[kc * (KB / 4) + c4];
      }
      *reinterpret_cast<float4*>(&sA[r][c4 * 4]) = v;
    }
    __syncthreads();
    #pragma unroll 4
    for (int k = 0; k < KB; ++k) {
      float a[4];
      float wv[CW];
      #pragma unroll
      for (int i = 0; i < 4; ++i) a[i] = sA[ty * 4 + i][k];   // broadcast within lane groups
      #pragma unroll
      for (int h = 0; h < CW / 4; ++h) {
        float4 w4 = *reinterpret_cast<const float4*>(&sW[k][tx * 4 + 64 * h]);
        wv[h * 4 + 0] = w4.x; wv[h * 4 + 1] = w4.y; wv[h * 4 + 2] = w4.z; wv[h * 4 + 3] = w4.w;
      }
      #pragma unroll
      for (int i = 0; i < 4; ++i)
        #pragma unroll
        for (int j = 0; j < CW; ++j)
          acc[i][j] = fmaf(a[i], wv[j], acc[i][j]);
    }
  }
  // optional fused projections (raw acc, before activation — H1 gemm has none anyway)
  if (DO_PROJ) {
    float s4v[CW], n4v[CW];
    #pragma unroll
    for (int h = 0; h < CW / 4; ++h) {
      float4 s4 = *reinterpret_cast<const float4*>(a_s + tx * 4 + 64 * h);
      float4 n4 = *reinterpret_cast<const float4*>(a_n + tx * 4 + 64 * h);
      s4v[h*4+0]=s4.x; s4v[h*4+1]=s4.y; s4v[h*4+2]=s4.z; s4v[h*4+3]=s4.w;
      n4v[h*4+0]=n4.x; n4v[h*4+1]=n4.y; n4v[h*4+2]=n4.z; n4v[h*4+3]=n4.w;
    }
    #pragma unroll
    for (int i = 0; i < 4; ++i) {
      float ds = 0.f, dn = 0.f;
      #pragma unroll
      for (int j = 0; j < CW; ++j) { ds = fmaf(acc[i][j], s4v[j], ds); dn = fmaf(acc[i][j], n4v[j], dn); }
      #pragma unroll
      for (int o = 1; o < 16; o <<= 1) { ds += __shfl_xor(ds, o, 64); dn += __shfl_xor(dn, o, 64); }
      int gr = row0 + ty * 4 + i;
      if (tx == 0 && gr < M) { as_o[gr] = ds; an_o[gr] = dn; }
    }
  }
  // epilogue: cols for thread = tx*4 + 64*h, float4 stores
  #pragma unroll
  for (int i = 0; i < 4; ++i) {
    int gr = row0 + ty * 4 + i;
    if (gr >= M) continue;
    long rrow = 0;
    if (HAS_RES) rrow = ridx ? (long)ridx[gr] : (long)gr;
    #pragma unroll
    for (int h = 0; h < CW / 4; ++h) {
      int c = tx * 4 + 64 * h;
      float4 v = make_float4(acc[i][h*4+0], acc[i][h*4+1], acc[i][h*4+2], acc[i][h*4+3]);
      if (HAS_BIAS) {
        float4 bv = *reinterpret_cast<const float4*>(bias + c);
        v.x += bv.x; v.y += bv.y; v.z += bv.z; v.w += bv.w;
      }
      if (DO_ELU) {
        v.x = (v.x > 0.f) ? v.x : (__expf(v.x) - 1.f);
        v.y = (v.y > 0.f) ? v.y : (__expf(v.y) - 1.f);
        v.z = (v.z > 0.f) ? v.z : (__expf(v.z) - 1.f);
        v.w = (v.w > 0.f) ? v.w : (__expf(v.w) - 1.f);
      }
      if (HAS_RES) {
        float4 rv = *reinterpret_cast<const float4*>(Res + rrow * NC + c);
        v.x += rv.x; v.y += rv.y; v.z += rv.z; v.w += rv.w;
      }
      *reinterpret_cast<float4*>(C + (long)gr * NC + c) = v;
    }
  }
}

// ---------------- needed-dst flags (bytes) -------------
__global__ void flags_kernel(const int* __restrict__ ui, const int* __restrict__ ii, int B,
                             unsigned char* __restrict__ nfu, unsigned char* __restrict__ nfb)
{
  int i = blockIdx.x * blockDim.x + threadIdx.x;
  if (i < B) { nfu[ui[i]] = 1; nfb[ii[i]] = 1; }
}

// ---------------- pass 1: gated count + score + per-block dense append ----------
// 8 edges/thread (int4 loads -> 8 independent gather/atomic chains in flight),
// unconditional coalesced gc stream (independent of flag gather), ballot compaction.
// rel = in-segment slot (counting-sort); entries packed {src, dst, rel, sc_bits}.
__global__ __launch_bounds__(256) void edge_prep(
    const int* __restrict__ src, const int* __restrict__ dst,
    const unsigned char* __restrict__ flag,
    const float* __restrict__ as_, const float* __restrict__ an_,
    const float* __restrict__ gc, const float* __restrict__ omega,
    int* __restrict__ deg, int4* __restrict__ cmp, int* __restrict__ blkcnt, int E)
{
  __shared__ int lcnt;
  if (threadIdx.x == 0) lcnt = 0;
  __syncthreads();
  const int lane = threadIdx.x & 63;
  const long base = (long)blockIdx.x * 2048;
  const int e0 = (int)base + threadIdx.x * 8;

  int d[8], s[8];
  bool act[8];
  const bool full = (e0 + 7 < E);
  if (full) {
    #pragma unroll
    for (int q = 0; q < 2; ++q) {
      int4 d4 = *reinterpret_cast<const int4*>(dst + e0 + q * 4);
      int4 s4 = *reinterpret_cast<const int4*>(src + e0 + q * 4);
      d[q*4+0]=d4.x; d[q*4+1]=d4.y; d[q*4+2]=d4.z; d[q*4+3]=d4.w;
      s[q*4+0]=s4.x; s[q*4+1]=s4.y; s[q*4+2]=s4.z; s[q*4+3]=s4.w;
    }
    #pragma unroll
    for (int j = 0; j < 8; ++j) act[j] = true;
  } else {
    #pragma unroll
    for (int j = 0; j < 8; ++j) {
      act[j] = (e0 + j < E);
      d[j] = act[j] ? dst[e0 + j] : 0;
      s[j] = act[j] ? src[e0 + j] : 0;
    }
  }
  // omega weights: unconditional coalesced stream (independent of flag gathers)
  float uw[8];
  if (gc) {
    float o0 = omega[0], o1 = omega[1], o2 = omega[2];
    if (full) {
      float g[24];
      const float4* gp = reinterpret_cast<const float4*>(gc + (long)e0 * 3);
      #pragma unroll
      for (int q = 0; q < 6; ++q) *reinterpret_cast<float4*>(&g[q*4]) = gp[q];
      #pragma unroll
      for (int j = 0; j < 8; ++j) uw[j] = g[j*3+0]*o0 + g[j*3+1]*o1 + g[j*3+2]*o2;
    } else {
      #pragma unroll
      for (int j = 0; j < 8; ++j) {
        uw[j] = 0.f;
        if (act[j]) {
          long e = e0 + j;
          uw[j] = gc[e*3+0]*o0 + gc[e*3+1]*o1 + gc[e*3+2]*o2;
        }
      }
    }
  }
  // independent flag gathers
  #pragma unroll
  for (int j = 0; j < 8; ++j) if (act[j]) act[j] = (flag[d[j]] != 0);
  // scores (independent gathers for active)
  float sc[8];
  #pragma unroll
  for (int j = 0; j < 8; ++j) {
    float v = 0.f;
    if (act[j]) {
      v = as_[d[j]] + an_[s[j]];
      if (gc) v *= uw[j];
      v = (v >= 0.f) ? v : 0.2f * v;     // leaky_relu 0.2
    }
    sc[j] = v;
  }
  // per-sub-edge ballot compaction (1 LDS atomic per wave per sub-edge)
  #pragma unroll
  for (int j = 0; j < 8; ++j) {
    unsigned long long m = __ballot(act[j]);
    if (m == 0ull) continue;
    int nw = __popcll(m);
    int pref = __popcll(m & ((1ull << lane) - 1ull));
    int wb = 0;
    if (lane == 0) wb = atomicAdd(&lcnt, nw);
    wb = __shfl(wb, 0, 64);
    if (act[j]) {
      int rel = atomicAdd(&deg[d[j]], 1);
      cmp[base + wb + pref] = make_int4(s[j], d[j], rel, __float_as_int(sc[j]));
    }
  }
  __syncthreads();
  if (threadIdx.x == 0) blkcnt[blockIdx.x] = lcnt;
}

// ---------------- pass 2: per-flagged-node compact slot + segment offsets ----------
__global__ __launch_bounds__(256) void offset_kernel(
    const unsigned char* __restrict__ flag, const int* __restrict__ deg,
    int* __restrict__ offs, int* __restrict__ dlist, int* __restrict__ g2c,
    int* __restrict__ cnt, int N)
{
  int i = blockIdx.x * 256 + threadIdx.x;
  if (i >= N || !flag[i]) return;
  int l = atomicAdd(&cnt[1], 1);
  g2c[i] = l;
  dlist[l] = i;
  int dg = deg[i];
  if (dg > 0) offs[i] = atomicAdd(&cnt[0], dg);
}

// ---------------- pass 3: place packed (src,sc) at offs[d]+rel — no atomics ----------
__global__ __launch_bounds__(256) void edge_place(
    const int4* __restrict__ cmp, const int* __restrict__ blkcnt,
    const int* __restrict__ offs, int2* __restrict__ eline)
{
  int nb = blkcnt[blockIdx.x];
  const long base = (long)blockIdx.x * 2048;
  for (int k = threadIdx.x; k < nb; k += 256) {
    int4 c = cmp[base + k];
    int pos = offs[c.y] + c.z;
    eline[pos] = make_int2(c.x, c.w);
  }
}

// ---------------- wave-per-dst softmax + aggregation (compact output) ----------
// No segment-max pass: scores are bounded (|sc| <~ 50), exp() in fp32 is safe.
__global__ __launch_bounds__(256) void aggr_kernel(
    const int* __restrict__ dlist, const int* __restrict__ cnt,
    const int* __restrict__ offs, const int* __restrict__ deg,
    const int2* __restrict__ eline,
    const float* __restrict__ H1, float* __restrict__ Houtc)
{
  int wid  = (int)((blockIdx.x * 256 + threadIdx.x) >> 6);
  int lane = threadIdx.x & 63;
  if (wid >= cnt[1]) return;
  int d = dlist[wid];
  int n = deg[d];
  float2* op = reinterpret_cast<float2*>(Houtc + (long)wid * KD) + lane;
  if (n == 0) { *op = make_float2(0.f, 0.f); return; }
  int st = offs[d];
  // segment sum of exp
  float ssum = 0.f;
  for (int i = lane; i < n; i += 64) ssum += __expf(__int_as_float(eline[st + i].y));
  #pragma unroll
  for (int o = 32; o; o >>= 1) ssum += __shfl_xor(ssum, o, 64);
  float inv = 1.f / ssum;
  // weighted aggregation: each lane owns 2 columns; rows read coalesced, 4-way MLP
  float ax = 0.f, ay = 0.f;
  int i = 0;
  for (; i + 4 <= n; i += 4) {
    int2 e0 = eline[st + i], e1 = eline[st + i + 1], e2 = eline[st + i + 2], e3 = eline[st + i + 3];
    float a0 = __expf(__int_as_float(e0.y));
    float a1 = __expf(__int_as_float(e1.y));
    float a2 = __expf(__int_as_float(e2.y));
    float a3 = __expf(__int_as_float(e3.y));
    const float2 h0 = *reinterpret_cast<const float2*>(H1 + (long)e0.x * KD + lane * 2);
    const float2 h1 = *reinterpret_cast<const float2*>(H1 + (long)e1.x * KD + lane * 2);
    const float2 h2 = *reinterpret_cast<const float2*>(H1 + (long)e2.x * KD + lane * 2);
    const float2 h3 = *reinterpret_cast<const float2*>(H1 + (long)e3.x * KD + lane * 2);
    ax = fmaf(h0.x, a0, ax); ay = fmaf(h0.y, a0, ay);
    ax = fmaf(h1.x, a1, ax); ay = fmaf(h1.y, a1, ay);
    ax = fmaf(h2.x, a2, ax); ay = fmaf(h2.y, a2, ay);
    ax = fmaf(h3.x, a3, ax); ay = fmaf(h3.y, a3, ay);
  }
  for (; i < n; ++i) {
    int2 e0 = eline[st + i];
    float a0 = __expf(__int_as_float(e0.y));
    const float2 h0 = *reinterpret_cast<const float2*>(H1 + (long)e0.x * KD + lane * 2);
    ax = fmaf(h0.x, a0, ax); ay = fmaf(h0.y, a0, ay);
  }
  *op = make_float2(ax * inv, ay * inv);
}

// ---------------- final: dot + biases + sigmoid -------------
__global__ __launch_bounds__(256) void final_kernel(
    const float* __restrict__ Ug, const float* __restrict__ Bg,
    const int* __restrict__ ui, const int* __restrict__ ii,
    const float* __restrict__ bias_u, const float* __restrict__ bias_b,
    const float* __restrict__ bx, float* __restrict__ out, int B)
{
  int wid  = (int)((blockIdx.x * 256 + threadIdx.x) >> 6);
  int lane = threadIdx.x & 63;
  if (wid >= B) return;
  float v = Ug[(long)wid * 64 + lane] * Bg[(long)wid * 64 + lane];
  #pragma unroll
  for (int o = 32; o > 0; o >>= 1) v += __shfl_xor(v, o, 64);
  if (lane == 0) {
    float raw = v + bias_u[ui[wid]] + bias_b[ii[wid]] + bx[0];
    out[wid] = 4.f / (1.f + __expf(-raw)) + 1.f;
  }
}

extern "C" void kernel_launch(void* const* d_in, const int* in_sizes, int n_in,
                              void* d_out, int out_size, void* d_ws, size_t ws_size,
                              hipStream_t stream)
{
  const int*   ui    = (const int*)  d_in[0];
  const int*   ii    = (const int*)  d_in[1];
  const float* S_u   = (const float*)d_in[2];
  const float* S_b   = (const float*)d_in[3];
  const int*   eu    = (const int*)  d_in[4];
  const int*   eb    = (const int*)  d_in[5];
  const float* gc    = (const float*)d_in[6];
  const float* W1_u  = (const float*)d_in[7];
  const float* a_s_u = (const float*)d_in[8];
  const float* a_n_u = (const float*)d_in[9];
  const float* W1_b  = (const float*)d_in[10];
  const float* a_s_b = (const float*)d_in[11];
  const float* a_n_b = (const float*)d_in[12];
  const float* omega = (const float*)d_in[13];
  const float* W_u2  = (const float*)d_in[14];
  const float* W_us2w= (const float*)d_in[15];
  const float* W_us2b= (const float*)d_in[16];
  const float* W_b2  = (const float*)d_in[17];
  const float* W_bs2w= (const float*)d_in[18];
  const float* W_bs2b= (const float*)d_in[19];
  const float* W_u3  = (const float*)d_in[20];
  const float* W_b3  = (const float*)d_in[21];
  const float* H_u4  = (const float*)d_in[22];
  const float* H_b4  = (const float*)d_in[23];
  const float* bias_u= (const float*)d_in[24];
  const float* bias_b= (const float*)d_in[25];
  const float* b_x   = (const float*)d_in[26];
  float* out = (float*)d_out;

  const int B  = in_sizes[0];
  const int NU = in_sizes[2] / KD;
  const int NI = in_sizes[3] / KD;
  const int EU = in_sizes[4] / 2;
  const int EB = in_sizes[5] / 2;
  const int GPU_ = (EU + 2047) / 2048;   // edge_prep grids (2048 edges/block)
  const int GPB_ = (EB + 2047) / 2048;

  char* w = (char*)d_ws;
  auto alloc = [&](size_t bytes) -> void* {
    void* r = (void*)w;
    w += (bytes + 255) & ~(size_t)255;
    return r;
  };
  // ---- zero-initialized region (one small memset per call) ----
  int* deg_u = (int*)alloc((size_t)NU * 4);
  int* deg_b = (int*)alloc((size_t)NI * 4);
  unsigned char* nfu = (unsigned char*)alloc((size_t)NU);
  unsigned char* nfb = (unsigned char*)alloc((size_t)NI);
  int* cnt   = (int*)alloc(16 * 4);          // [0,1]=user {edges,dsts}, [2,3]=item
  size_t zbytes = (size_t)(w - (char*)d_ws);
  // ---- scratch (fully written before read each call) ----
  int*   offs_u = (int*)  alloc((size_t)NU * 4);
  int*   offs_b = (int*)  alloc((size_t)NI * 4);
  int*   g2c_u  = (int*)  alloc((size_t)NU * 4);
  int*   g2c_b  = (int*)  alloc((size_t)NI * 4);
  int*   dl_u   = (int*)  alloc((size_t)B * 4);
  int*   dl_b   = (int*)  alloc((size_t)B * 4);
  int*   bc_u   = (int*)  alloc((size_t)GPU_ * 4);
  int*   bc_b   = (int*)  alloc((size_t)GPB_ * 4);
  int4*  cmp_u  = (int4*) alloc((size_t)GPU_ * 2048 * 16);
  int4*  cmp_b  = (int4*) alloc((size_t)GPB_ * 2048 * 16);
  int2*  el_u   = (int2*) alloc((size_t)EU * 8);
  int2*  el_b   = (int2*) alloc((size_t)EB * 8);
  float* H1u  = (float*)alloc((size_t)NU * KD * 4);
  float* H1b  = (float*)alloc((size_t)NI * KD * 4);
  float* Hu2c = (float*)alloc((size_t)B * KD * 4);
  float* Hb2c = (float*)alloc((size_t)B * KD * 4);
  float* asu  = (float*)alloc((size_t)NU * 4);
  float* anu  = (float*)alloc((size_t)NU * 4);
  float* asb  = (float*)alloc((size_t)NI * 4);
  float* anb  = (float*)alloc((size_t)NI * 4);
  float* Hu3g = (float*)alloc((size_t)B * KD * 4);
  float* Hb3g = (float*)alloc((size_t)B * KD * 4);
  float* Ug   = (float*)alloc((size_t)B * 64 * 4);
  float* Bg   = (float*)alloc((size_t)B * 64 * 4);
  (void)ws_size; (void)n_in; (void)out_size;

  hipMemsetAsync(d_ws, 0, zbytes, stream);

  flags_kernel<<<(B + 255) / 256, 256, 0, stream>>>(ui, ii, B, nfu, nfb);

  // H1 = S @ W1, with fused per-row projections as/an
  gemm_k128<128,false,false,false,false,true><<<(NU + 63) / 64, 256, 0, stream>>>(
      S_u, W1_u, nullptr, nullptr, nullptr, nullptr, nullptr, nullptr, nullptr,
      NU, H1u, a_s_u, a_n_u, asu, anu);
  gemm_k128<128,false,false,false,false,true><<<(NI + 63) / 64, 256, 0, stream>>>(
      S_b, W1_b, nullptr, nullptr, nullptr, nullptr, nullptr, nullptr, nullptr,
      NI, H1b, a_s_b, a_n_b, asb, anb);

  edge_prep<<<GPU_, 256, 0, stream>>>(eu, eu + EU, nfu, asu, anu, nullptr, nullptr,
                                      deg_u, cmp_u, bc_u, EU);
  edge_prep<<<GPB_, 256, 0, stream>>>(eb, eb + EB, nfb, asb, anb, gc, omega,
                                      deg_b, cmp_b, bc_b, EB);

  offset_kernel<<<(NU + 255) / 256, 256, 0, stream>>>(nfu, deg_u, offs_u, dl_u, g2c_u, cnt + 0, NU);
  offset_kernel<<<(NI + 255) / 256, 256, 0, stream>>>(nfb, deg_b, offs_b, dl_b, g2c_b, cnt + 2, NI);

  edge_place<<<GPU_, 256, 0, stream>>>(cmp_u, bc_u, offs_u, el_u);
  edge_place<<<GPB_, 256, 0, stream>>>(cmp_b, bc_b, offs_b, el_b);

  aggr_kernel<<<(B * 64 + 255) / 256, 256, 0, stream>>>(dl_u, cnt + 0, offs_u, deg_u, el_u, H1u, Hu2c);
  aggr_kernel<<<(B * 64 + 255) / 256, 256, 0, stream>>>(dl_b, cnt + 2, offs_b, deg_b, el_b, H1b, Hb2c);

  // Hu3 = elu(Hu2c[g2c[ui]] @ W_u2 + S_u[ui] @ W_us2 + b)
  gemm_k128<128,true,true,true,false,false><<<(B + 63) / 64, 256, 0, stream>>>(
      Hu2c, W_u2, S_u, W_us2w, W_us2b, nullptr, ui, g2c_u, nullptr,
      B, Hu3g, nullptr, nullptr, nullptr, nullptr);
  gemm_k128<128,true,true,true,false,false><<<(B + 63) / 64, 256, 0, stream>>>(
      Hb2c, W_b2, S_b, W_bs2w, W_bs2b, nullptr, ii, g2c_b, nullptr,
      B, Hb3g, nullptr, nullptr, nullptr, nullptr);

  // U = elu(Hu3 @ W_u3) + H_u4[ui]
  gemm_k128<64,false,false,true,true,false><<<(B + 63) / 64, 256, 0, stream>>>(
      Hu3g, W_u3, nullptr, nullptr, nullptr, H_u4, nullptr, nullptr, ui,
      B, Ug, nullptr, nullptr, nullptr, nullptr);
  gemm_k128<64,false,false,true,true,false><<<(B + 63) / 64, 256, 0, stream>>>(
      Hb3g, W_b3, nullptr, nullptr, nullptr, H_b4, nullptr, nullptr, ii,
      B, Bg, nullptr, nullptr, nullptr, nullptr);

  final_kernel<<<(B + 3) / 4, 256, 0, stream>>>(Ug, Bg, ui, ii, bias_u, bias_b, b_x, out, B);
}

// Round 9
// 383.781 us; speedup vs baseline: 5.4478x; 1.0883x over previous
//
#include <hip/hip_runtime.h>
#include <hip/hip_bf16.h>

#define KD 128
#define NANF __int_as_float(0x7fc00000)

// ---------------- dual-grid generic K=128 GEMM ----------------
// Blocks [0,split) run side A, [split,grid) side B. Per side:
// C = act(A1[map1[aidx[r]]]@W1 (+A2[aidx[r]]@W2) (+bias)) (+Res[ridx[r]])
// DO_PROJ: as_o = flag ? row@a_s : NaN ; an_o = row@a_n  (NaN = inactive sentinel).
template<int NC, bool HAS_A2, bool HAS_BIAS, bool DO_ELU, bool HAS_RES, bool DO_PROJ>
__global__ __launch_bounds__(256, 3) void gemm_dual(
    int split,
    const float* __restrict__ A1a, const float* __restrict__ W1a,
    const float* __restrict__ A2a, const float* __restrict__ W2a,
    const float* __restrict__ biasa, const float* __restrict__ Resa,
    const int* __restrict__ aidxa, const int* __restrict__ map1a,
    const int* __restrict__ ridxa, int Ma, float* __restrict__ Ca,
    const float* __restrict__ a_sa, const float* __restrict__ a_na,
    float* __restrict__ as_oa, float* __restrict__ an_oa,
    const unsigned char* __restrict__ fla,
    const float* __restrict__ A1b, const float* __restrict__ W1b,
    const float* __restrict__ A2b, const float* __restrict__ W2b,
    const float* __restrict__ biasb, const float* __restrict__ Resb,
    const int* __restrict__ aidxb, const int* __restrict__ map1b,
    const int* __restrict__ ridxb, int Mb, float* __restrict__ Cb,
    const float* __restrict__ a_sb, const float* __restrict__ a_nb,
    float* __restrict__ as_ob, float* __restrict__ an_ob,
    const unsigned char* __restrict__ flb)
{
  const bool sB = (int)blockIdx.x >= split;
  const float* A1 = sB ? A1b : A1a;  const float* W1 = sB ? W1b : W1a;
  const float* A2 = sB ? A2b : A2a;  const float* W2 = sB ? W2b : W2a;
  const float* bias = sB ? biasb : biasa;  const float* Res = sB ? Resb : Resa;
  const int* aidx = sB ? aidxb : aidxa;    const int* map1 = sB ? map1b : map1a;
  const int* ridx = sB ? ridxb : ridxa;
  const int M = sB ? Mb : Ma;  float* C = sB ? Cb : Ca;
  const float* a_s = sB ? a_sb : a_sa;  const float* a_n = sB ? a_nb : a_na;
  float* as_o = sB ? as_ob : as_oa;     float* an_o = sB ? an_ob : an_oa;
  const unsigned char* fl = sB ? flb : fla;
  const int bid = sB ? ((int)blockIdx.x - split) : (int)blockIdx.x;

  constexpr int CW = NC / 16;
  constexpr int KB = 64;
  constexpr int NAF4 = 64 * KB / 4 / 256;
  constexpr int NWF4 = KB * NC / 4 / 256;
  __shared__ float sA[64][KB + 4];
  __shared__ float sW[KB][NC];
  const int t  = threadIdx.x;
  const int ty = t >> 4, tx = t & 15;
  const int row0 = bid * 64;

  float acc[4][CW];
  #pragma unroll
  for (int i = 0; i < 4; ++i)
    #pragma unroll
    for (int j = 0; j < CW; ++j) acc[i][j] = 0.f;

  const int npass = HAS_A2 ? 2 : 1;
  const int NCH = npass * (KD / KB);

  for (int cc = 0; cc < NCH; ++cc) {
    const float* Am = (cc < 2) ? A1 : A2;
    const float* Wm = (cc < 2) ? W1 : W2;
    const int* mp   = (cc < 2) ? map1 : nullptr;
    const int kc = cc & 1;
    if (cc) __syncthreads();
    {
      const float4* Wp = reinterpret_cast<const float4*>(Wm) + (long)kc * (KB * NC / 4);
      #pragma unroll
      for (int q = 0; q < NWF4; ++q)
        reinterpret_cast<float4*>(&sW[0][0])[t + 256 * q] = Wp[t + 256 * q];
    }
    #pragma unroll
    for (int q = 0; q < NAF4; ++q) {
      int p  = t + 256 * q;
      int r  = p >> 4, c4 = p & 15;
      float4 v = make_float4(0.f, 0.f, 0.f, 0.f);
      int gr = row0 + r;
      if (gr < M) {
        long grow = aidx ? (long)aidx[gr] : (long)gr;
        if (mp) grow = mp[grow];
        v = reinterpret_cast<const float4*>(Am + grow * KD)[kc * (KB / 4) + c4];
      }
      *reinterpret_cast<float4*>(&sA[r][c4 * 4]) = v;
    }
    __syncthreads();
    #pragma unroll 4
    for (int k = 0; k < KB; ++k) {
      float a[4];
      float wv[CW];
      #pragma unroll
      for (int i = 0; i < 4; ++i) a[i] = sA[ty * 4 + i][k];
      #pragma unroll
      for (int h = 0; h < CW / 4; ++h) {
        float4 w4 = *reinterpret_cast<const float4*>(&sW[k][tx * 4 + 64 * h]);
        wv[h * 4 + 0] = w4.x; wv[h * 4 + 1] = w4.y; wv[h * 4 + 2] = w4.z; wv[h * 4 + 3] = w4.w;
      }
      #pragma unroll
      for (int i = 0; i < 4; ++i)
        #pragma unroll
        for (int j = 0; j < CW; ++j)
          acc[i][j] = fmaf(a[i], wv[j], acc[i][j]);
    }
  }
  if (DO_PROJ) {
    float s4v[CW], n4v[CW];
    #pragma unroll
    for (int h = 0; h < CW / 4; ++h) {
      float4 s4 = *reinterpret_cast<const float4*>(a_s + tx * 4 + 64 * h);
      float4 n4 = *reinterpret_cast<const float4*>(a_n + tx * 4 + 64 * h);
      s4v[h*4+0]=s4.x; s4v[h*4+1]=s4.y; s4v[h*4+2]=s4.z; s4v[h*4+3]=s4.w;
      n4v[h*4+0]=n4.x; n4v[h*4+1]=n4.y; n4v[h*4+2]=n4.z; n4v[h*4+3]=n4.w;
    }
    #pragma unroll
    for (int i = 0; i < 4; ++i) {
      float ds = 0.f, dn = 0.f;
      #pragma unroll
      for (int j = 0; j < CW; ++j) { ds = fmaf(acc[i][j], s4v[j], ds); dn = fmaf(acc[i][j], n4v[j], dn); }
      #pragma unroll
      for (int o = 1; o < 16; o <<= 1) { ds += __shfl_xor(ds, o, 64); dn += __shfl_xor(dn, o, 64); }
      int gr = row0 + ty * 4 + i;
      if (tx == 0 && gr < M) {
        as_o[gr] = fl[gr] ? ds : NANF;   // NaN sentinel = dst not needed
        an_o[gr] = dn;
      }
    }
  }
  #pragma unroll
  for (int i = 0; i < 4; ++i) {
    int gr = row0 + ty * 4 + i;
    if (gr >= M) continue;
    long rrow = 0;
    if (HAS_RES) rrow = ridx ? (long)ridx[gr] : (long)gr;
    #pragma unroll
    for (int h = 0; h < CW / 4; ++h) {
      int c = tx * 4 + 64 * h;
      float4 v = make_float4(acc[i][h*4+0], acc[i][h*4+1], acc[i][h*4+2], acc[i][h*4+3]);
      if (HAS_BIAS) {
        float4 bv = *reinterpret_cast<const float4*>(bias + c);
        v.x += bv.x; v.y += bv.y; v.z += bv.z; v.w += bv.w;
      }
      if (DO_ELU) {
        v.x = (v.x > 0.f) ? v.x : (__expf(v.x) - 1.f);
        v.y = (v.y > 0.f) ? v.y : (__expf(v.y) - 1.f);
        v.z = (v.z > 0.f) ? v.z : (__expf(v.z) - 1.f);
        v.w = (v.w > 0.f) ? v.w : (__expf(v.w) - 1.f);
      }
      if (HAS_RES) {
        float4 rv = *reinterpret_cast<const float4*>(Res + rrow * NC + c);
        v.x += rv.x; v.y += rv.y; v.z += rv.z; v.w += rv.w;
      }
      *reinterpret_cast<float4*>(C + (long)gr * NC + c) = v;
    }
  }
}

// ---------------- needed-dst flags -------------
__global__ void flags_kernel(const int* __restrict__ ui, const int* __restrict__ ii, int B,
                             unsigned char* __restrict__ nfu, unsigned char* __restrict__ nfb)
{
  int i = blockIdx.x * blockDim.x + threadIdx.x;
  if (i < B) { nfu[ui[i]] = 1; nfb[ii[i]] = 1; }
}

// ---------------- dual pass 1: score + count + per-block dense append ----------
// Active test = !isnan(as_[d]) (sentinel written by gemm1) — single gather chain.
// 8 edges/thread, ballot compaction, {src,dst,rel,sc} packed per block window.
__global__ __launch_bounds__(256) void edge_prep_dual(
    int split,
    const int* __restrict__ srcA, const int* __restrict__ dstA,
    const float* __restrict__ asA, const float* __restrict__ anA,
    int* __restrict__ degA, int4* __restrict__ cmpA, int* __restrict__ bcA, int EA,
    const int* __restrict__ srcB, const int* __restrict__ dstB,
    const float* __restrict__ asB, const float* __restrict__ anB,
    const float* __restrict__ gc, const float* __restrict__ omega,
    int* __restrict__ degB, int4* __restrict__ cmpB, int* __restrict__ bcB, int EB_)
{
  const bool sB = (int)blockIdx.x >= split;
  const int* src = sB ? srcB : srcA;  const int* dst = sB ? dstB : dstA;
  const float* as_ = sB ? asB : asA;  const float* an_ = sB ? anB : anA;
  int* deg = sB ? degB : degA;  int4* cmp = sB ? cmpB : cmpA;
  int* blkcnt = sB ? bcB : bcA;
  const int E = sB ? EB_ : EA;
  const float* gcp = sB ? gc : nullptr;
  const int bid = sB ? ((int)blockIdx.x - split) : (int)blockIdx.x;

  __shared__ int lcnt;
  if (threadIdx.x == 0) lcnt = 0;
  __syncthreads();
  const int lane = threadIdx.x & 63;
  const long base = (long)bid * 2048;
  const int e0 = (int)base + threadIdx.x * 8;

  int d[8], s[8];
  bool act[8];
  const bool full = (e0 + 7 < E);
  if (full) {
    #pragma unroll
    for (int q = 0; q < 2; ++q) {
      int4 d4 = *reinterpret_cast<const int4*>(dst + e0 + q * 4);
      int4 s4 = *reinterpret_cast<const int4*>(src + e0 + q * 4);
      d[q*4+0]=d4.x; d[q*4+1]=d4.y; d[q*4+2]=d4.z; d[q*4+3]=d4.w;
      s[q*4+0]=s4.x; s[q*4+1]=s4.y; s[q*4+2]=s4.z; s[q*4+3]=s4.w;
    }
    #pragma unroll
    for (int j = 0; j < 8; ++j) act[j] = true;
  } else {
    #pragma unroll
    for (int j = 0; j < 8; ++j) {
      act[j] = (e0 + j < E);
      d[j] = act[j] ? dst[e0 + j] : 0;
      s[j] = act[j] ? src[e0 + j] : 0;
    }
  }
  // omega weights: unconditional coalesced stream
  float uw[8];
  if (gcp) {
    float o0 = omega[0], o1 = omega[1], o2 = omega[2];
    if (full) {
      float g[24];
      const float4* gp = reinterpret_cast<const float4*>(gcp + (long)e0 * 3);
      #pragma unroll
      for (int q = 0; q < 6; ++q) *reinterpret_cast<float4*>(&g[q*4]) = gp[q];
      #pragma unroll
      for (int j = 0; j < 8; ++j) uw[j] = g[j*3+0]*o0 + g[j*3+1]*o1 + g[j*3+2]*o2;
    } else {
      #pragma unroll
      for (int j = 0; j < 8; ++j) {
        uw[j] = 0.f;
        if (act[j]) {
          long e = e0 + j;
          uw[j] = gcp[e*3+0]*o0 + gcp[e*3+1]*o1 + gcp[e*3+2]*o2;
        }
      }
    }
  }
  // independent gathers: as_[d] (NaN = inactive) and an_[s]
  float vas[8], van[8];
  #pragma unroll
  for (int j = 0; j < 8; ++j) vas[j] = as_[d[j]];
  #pragma unroll
  for (int j = 0; j < 8; ++j) van[j] = an_[s[j]];
  float sc[8];
  #pragma unroll
  for (int j = 0; j < 8; ++j) {
    act[j] = act[j] && (vas[j] == vas[j]);
    float v = vas[j] + van[j];
    if (gcp) v *= uw[j];
    sc[j] = (v >= 0.f) ? v : 0.2f * v;   // leaky_relu 0.2
  }
  // per-sub-edge ballot compaction
  #pragma unroll
  for (int j = 0; j < 8; ++j) {
    unsigned long long m = __ballot(act[j]);
    if (m == 0ull) continue;
    int nw = __popcll(m);
    int pref = __popcll(m & ((1ull << lane) - 1ull));
    int wb = 0;
    if (lane == 0) wb = atomicAdd(&lcnt, nw);
    wb = __shfl(wb, 0, 64);
    if (act[j]) {
      int rel = atomicAdd(&deg[d[j]], 1);
      cmp[base + wb + pref] = make_int4(s[j], d[j], rel, __float_as_int(sc[j]));
    }
  }
  __syncthreads();
  if (threadIdx.x == 0) blkcnt[bid] = lcnt;
}

// ---------------- dual pass 2: compact slot + segment offsets ----------
__global__ __launch_bounds__(256) void offset_dual(
    int split,
    const unsigned char* __restrict__ flA, const int* __restrict__ degA,
    int* __restrict__ offsA, int* __restrict__ dlA, int* __restrict__ g2cA,
    int* __restrict__ cntA, int NA,
    const unsigned char* __restrict__ flB, const int* __restrict__ degB,
    int* __restrict__ offsB, int* __restrict__ dlB, int* __restrict__ g2cB,
    int* __restrict__ cntB, int NB)
{
  const bool sB = (int)blockIdx.x >= split;
  const unsigned char* flag = sB ? flB : flA;
  const int* deg = sB ? degB : degA;
  int* offs = sB ? offsB : offsA;  int* dlist = sB ? dlB : dlA;
  int* g2c = sB ? g2cB : g2cA;     int* cnt = sB ? cntB : cntA;
  const int N = sB ? NB : NA;
  const int bid = sB ? ((int)blockIdx.x - split) : (int)blockIdx.x;

  int i = bid * 256 + threadIdx.x;
  if (i >= N || !flag[i]) return;
  int l = atomicAdd(&cnt[1], 1);
  g2c[i] = l;
  dlist[l] = i;
  int dg = deg[i];
  if (dg > 0) offs[i] = atomicAdd(&cnt[0], dg);
}

// ---------------- dual pass 3: place packed (src,sc) — no atomics ----------
__global__ __launch_bounds__(256) void place_dual(
    int split,
    const int4* __restrict__ cmpA, const int* __restrict__ bcA,
    const int* __restrict__ offsA, int2* __restrict__ elA,
    const int4* __restrict__ cmpB, const int* __restrict__ bcB,
    const int* __restrict__ offsB, int2* __restrict__ elB)
{
  const bool sB = (int)blockIdx.x >= split;
  const int4* cmp = sB ? cmpB : cmpA;
  const int* blkcnt = sB ? bcB : bcA;
  const int* offs = sB ? offsB : offsA;
  int2* eline = sB ? elB : elA;
  const int bid = sB ? ((int)blockIdx.x - split) : (int)blockIdx.x;

  int nb = blkcnt[bid];
  const long base = (long)bid * 2048;
  for (int k = threadIdx.x; k < nb; k += 256) {
    int4 c = cmp[base + k];
    int pos = offs[c.y] + c.z;
    eline[pos] = make_int2(c.x, c.w);
  }
}

// ---------------- dual wave-per-dst softmax + aggregation ----------
__global__ __launch_bounds__(256) void aggr_dual(
    int split,
    const int* __restrict__ dlA, const int* __restrict__ cntA,
    const int* __restrict__ offsA, const int* __restrict__ degA,
    const int2* __restrict__ elA, const float* __restrict__ H1A, float* __restrict__ HoA,
    const int* __restrict__ dlB, const int* __restrict__ cntB,
    const int* __restrict__ offsB, const int* __restrict__ degB,
    const int2* __restrict__ elB, const float* __restrict__ H1B, float* __restrict__ HoB)
{
  const bool sB = (int)blockIdx.x >= split;
  const int* dlist = sB ? dlB : dlA;  const int* cnt = sB ? cntB : cntA;
  const int* offs = sB ? offsB : offsA;  const int* deg = sB ? degB : degA;
  const int2* eline = sB ? elB : elA;
  const float* H1 = sB ? H1B : H1A;  float* Houtc = sB ? HoB : HoA;
  const int bid = sB ? ((int)blockIdx.x - split) : (int)blockIdx.x;

  int wid  = bid * 4 + (int)(threadIdx.x >> 6);
  int lane = threadIdx.x & 63;
  if (wid >= cnt[1]) return;
  int d = dlist[wid];
  int n = deg[d];
  float2* op = reinterpret_cast<float2*>(Houtc + (long)wid * KD) + lane;
  if (n == 0) { *op = make_float2(0.f, 0.f); return; }
  int st = offs[d];
  float ssum = 0.f;
  for (int i = lane; i < n; i += 64) ssum += __expf(__int_as_float(eline[st + i].y));
  #pragma unroll
  for (int o = 32; o; o >>= 1) ssum += __shfl_xor(ssum, o, 64);
  float inv = 1.f / ssum;
  float ax = 0.f, ay = 0.f;
  int i = 0;
  for (; i + 4 <= n; i += 4) {
    int2 e0 = eline[st + i], e1 = eline[st + i + 1], e2 = eline[st + i + 2], e3 = eline[st + i + 3];
    float a0 = __expf(__int_as_float(e0.y));
    float a1 = __expf(__int_as_float(e1.y));
    float a2 = __expf(__int_as_float(e2.y));
    float a3 = __expf(__int_as_float(e3.y));
    const float2 h0 = *reinterpret_cast<const float2*>(H1 + (long)e0.x * KD + lane * 2);
    const float2 h1 = *reinterpret_cast<const float2*>(H1 + (long)e1.x * KD + lane * 2);
    const float2 h2 = *reinterpret_cast<const float2*>(H1 + (long)e2.x * KD + lane * 2);
    const float2 h3 = *reinterpret_cast<const float2*>(H1 + (long)e3.x * KD + lane * 2);
    ax = fmaf(h0.x, a0, ax); ay = fmaf(h0.y, a0, ay);
    ax = fmaf(h1.x, a1, ax); ay = fmaf(h1.y, a1, ay);
    ax = fmaf(h2.x, a2, ax); ay = fmaf(h2.y, a2, ay);
    ax = fmaf(h3.x, a3, ax); ay = fmaf(h3.y, a3, ay);
  }
  for (; i < n; ++i) {
    int2 e0 = eline[st + i];
    float a0 = __expf(__int_as_float(e0.y));
    const float2 h0 = *reinterpret_cast<const float2*>(H1 + (long)e0.x * KD + lane * 2);
    ax = fmaf(h0.x, a0, ax); ay = fmaf(h0.y, a0, ay);
  }
  *op = make_float2(ax * inv, ay * inv);
}

// ---------------- final: dot + biases + sigmoid -------------
__global__ __launch_bounds__(256) void final_kernel(
    const float* __restrict__ Ug, const float* __restrict__ Bg,
    const int* __restrict__ ui, const int* __restrict__ ii,
    const float* __restrict__ bias_u, const float* __restrict__ bias_b,
    const float* __restrict__ bx, float* __restrict__ out, int B)
{
  int wid  = (int)((blockIdx.x * 256 + threadIdx.x) >> 6);
  int lane = threadIdx.x & 63;
  if (wid >= B) return;
  float v = Ug[(long)wid * 64 + lane] * Bg[(long)wid * 64 + lane];
  #pragma unroll
  for (int o = 32; o > 0; o >>= 1) v += __shfl_xor(v, o, 64);
  if (lane == 0) {
    float raw = v + bias_u[ui[wid]] + bias_b[ii[wid]] + bx[0];
    out[wid] = 4.f / (1.f + __expf(-raw)) + 1.f;
  }
}

extern "C" void kernel_launch(void* const* d_in, const int* in_sizes, int n_in,
                              void* d_out, int out_size, void* d_ws, size_t ws_size,
                              hipStream_t stream)
{
  const int*   ui    = (const int*)  d_in[0];
  const int*   ii    = (const int*)  d_in[1];
  const float* S_u   = (const float*)d_in[2];
  const float* S_b   = (const float*)d_in[3];
  const int*   eu    = (const int*)  d_in[4];
  const int*   eb    = (const int*)  d_in[5];
  const float* gc    = (const float*)d_in[6];
  const float* W1_u  = (const float*)d_in[7];
  const float* a_s_u = (const float*)d_in[8];
  const float* a_n_u = (const float*)d_in[9];
  const float* W1_b  = (const float*)d_in[10];
  const float* a_s_b = (const float*)d_in[11];
  const float* a_n_b = (const float*)d_in[12];
  const float* omega = (const float*)d_in[13];
  const float* W_u2  = (const float*)d_in[14];
  const float* W_us2w= (const float*)d_in[15];
  const float* W_us2b= (const float*)d_in[16];
  const float* W_b2  = (const float*)d_in[17];
  const float* W_bs2w= (const float*)d_in[18];
  const float* W_bs2b= (const float*)d_in[19];
  const float* W_u3  = (const float*)d_in[20];
  const float* W_b3  = (const float*)d_in[21];
  const float* H_u4  = (const float*)d_in[22];
  const float* H_b4  = (const float*)d_in[23];
  const float* bias_u= (const float*)d_in[24];
  const float* bias_b= (const float*)d_in[25];
  const float* b_x   = (const float*)d_in[26];
  float* out = (float*)d_out;

  const int B  = in_sizes[0];
  const int NU = in_sizes[2] / KD;
  const int NI = in_sizes[3] / KD;
  const int EU = in_sizes[4] / 2;
  const int EB = in_sizes[5] / 2;
  const int GPU_ = (EU + 2047) / 2048;
  const int GPB_ = (EB + 2047) / 2048;
  const int G1U = (NU + 63) / 64, G1I = (NI + 63) / 64;
  const int GOU = (NU + 255) / 256, GOI = (NI + 255) / 256;
  const int GAG = (B + 3) / 4;             // aggr blocks per side (4 waves/block, 1 wave/dst)
  const int GB  = (B + 63) / 64;           // gemm2/3 blocks per side

  char* w = (char*)d_ws;
  auto alloc = [&](size_t bytes) -> void* {
    void* r = (void*)w;
    w += (bytes + 255) & ~(size_t)255;
    return r;
  };
  // ---- zero-initialized region (one small memset per call) ----
  int* deg_u = (int*)alloc((size_t)NU * 4);
  int* deg_b = (int*)alloc((size_t)NI * 4);
  unsigned char* nfu = (unsigned char*)alloc((size_t)NU);
  unsigned char* nfb = (unsigned char*)alloc((size_t)NI);
  int* cnt   = (int*)alloc(16 * 4);          // [0,1]=user {edges,dsts}, [2,3]=item
  size_t zbytes = (size_t)(w - (char*)d_ws);
  // ---- scratch (fully written before read each call) ----
  int*   offs_u = (int*)  alloc((size_t)NU * 4);
  int*   offs_b = (int*)  alloc((size_t)NI * 4);
  int*   g2c_u  = (int*)  alloc((size_t)NU * 4);
  int*   g2c_b  = (int*)  alloc((size_t)NI * 4);
  int*   dl_u   = (int*)  alloc((size_t)B * 4);
  int*   dl_b   = (int*)  alloc((size_t)B * 4);
  int*   bc_u   = (int*)  alloc((size_t)GPU_ * 4);
  int*   bc_b   = (int*)  alloc((size_t)GPB_ * 4);
  int4*  cmp_u  = (int4*) alloc((size_t)GPU_ * 2048 * 16);
  int4*  cmp_b  = (int4*) alloc((size_t)GPB_ * 2048 * 16);
  int2*  el_u   = (int2*) alloc((size_t)EU * 8);
  int2*  el_b   = (int2*) alloc((size_t)EB * 8);
  float* H1u  = (float*)alloc((size_t)NU * KD * 4);
  float* H1b  = (float*)alloc((size_t)NI * KD * 4);
  float* Hu2c = (float*)alloc((size_t)B * KD * 4);
  float* Hb2c = (float*)alloc((size_t)B * KD * 4);
  float* asu  = (float*)alloc((size_t)NU * 4);
  float* anu  = (float*)alloc((size_t)NU * 4);
  float* asb  = (float*)alloc((size_t)NI * 4);
  float* anb  = (float*)alloc((size_t)NI * 4);
  float* Hu3g = (float*)alloc((size_t)B * KD * 4);
  float* Hb3g = (float*)alloc((size_t)B * KD * 4);
  float* Ug   = (float*)alloc((size_t)B * 64 * 4);
  float* Bg   = (float*)alloc((size_t)B * 64 * 4);
  (void)ws_size; (void)n_in; (void)out_size;

  hipMemsetAsync(d_ws, 0, zbytes, stream);

  flags_kernel<<<(B + 255) / 256, 256, 0, stream>>>(ui, ii, B, nfu, nfb);

  // H1 = S @ W1 (both graphs, one dispatch), fused proj + NaN flag sentinel
  gemm_dual<128,false,false,false,false,true><<<G1U + G1I, 256, 0, stream>>>(
      G1U,
      S_u, W1_u, nullptr, nullptr, nullptr, nullptr, nullptr, nullptr, nullptr,
      NU, H1u, a_s_u, a_n_u, asu, anu, nfu,
      S_b, W1_b, nullptr, nullptr, nullptr, nullptr, nullptr, nullptr, nullptr,
      NI, H1b, a_s_b, a_n_b, asb, anb, nfb);

  edge_prep_dual<<<GPU_ + GPB_, 256, 0, stream>>>(
      GPU_,
      eu, eu + EU, asu, anu, deg_u, cmp_u, bc_u, EU,
      eb, eb + EB, asb, anb, gc, omega, deg_b, cmp_b, bc_b, EB);

  offset_dual<<<GOU + GOI, 256, 0, stream>>>(
      GOU,
      nfu, deg_u, offs_u, dl_u, g2c_u, cnt + 0, NU,
      nfb, deg_b, offs_b, dl_b, g2c_b, cnt + 2, NI);

  place_dual<<<GPU_ + GPB_, 256, 0, stream>>>(
      GPU_,
      cmp_u, bc_u, offs_u, el_u,
      cmp_b, bc_b, offs_b, el_b);

  aggr_dual<<<GAG * 2, 256, 0, stream>>>(
      GAG,
      dl_u, cnt + 0, offs_u, deg_u, el_u, H1u, Hu2c,
      dl_b, cnt + 2, offs_b, deg_b, el_b, H1b, Hb2c);

  // H3 = elu(H2c[g2c[idx]] @ W2 + S[idx] @ Ws2 + b), both sides
  gemm_dual<128,true,true,true,false,false><<<GB * 2, 256, 0, stream>>>(
      GB,
      Hu2c, W_u2, S_u, W_us2w, W_us2b, nullptr, ui, g2c_u, nullptr,
      B, Hu3g, nullptr, nullptr, nullptr, nullptr, nullptr,
      Hb2c, W_b2, S_b, W_bs2w, W_bs2b, nullptr, ii, g2c_b, nullptr,
      B, Hb3g, nullptr, nullptr, nullptr, nullptr, nullptr);

  // U = elu(H3 @ W3) + H4[idx], both sides
  gemm_dual<64,false,false,true,true,false><<<GB * 2, 256, 0, stream>>>(
      GB,
      Hu3g, W_u3, nullptr, nullptr, nullptr, H_u4, nullptr, nullptr, ui,
      B, Ug, nullptr, nullptr, nullptr, nullptr, nullptr,
      Hb3g, W_b3, nullptr, nullptr, nullptr, H_b4, nullptr, nullptr, ii,
      B, Bg, nullptr, nullptr, nullptr, nullptr, nullptr);

  final_kernel<<<(B + 3) / 4, 256, 0, stream>>>(Ug, Bg, ui, ii, bias_u, bias_b, b_x, out, B);
}